// Round 1
// baseline (2771.782 us; speedup 1.0000x reference)
//
#include <hip/hip_runtime.h>
#include <math.h>

#define B_  32
#define L_  512
#define C_  512
#define H_  512
#define K_  16
#define P_  96
#define NB_ 4

// ---------------------------------------------------------------- helpers

__device__ __forceinline__ float gelu_f(float x) {
    return 0.5f * x * (1.0f + erff(x * 0.70710678118654752440f));
}

// block(256) dual sum reduce; call at most once per kernel
__device__ __forceinline__ void block_sum2_256(float& a, float& b) {
    __shared__ float la[4], lb[4];
    #pragma unroll
    for (int off = 32; off; off >>= 1) {
        a += __shfl_down(a, off);
        b += __shfl_down(b, off);
    }
    int wid = threadIdx.x >> 6;
    if ((threadIdx.x & 63) == 0) { la[wid] = a; lb[wid] = b; }
    __syncthreads();
    a = la[0] + la[1] + la[2] + la[3];
    b = lb[0] + lb[1] + lb[2] + lb[3];
}

// JAX threefry2x32, key = (k0,k1)
__device__ __forceinline__ void threefry2x32(unsigned k0, unsigned k1,
                                             unsigned& x0, unsigned& x1) {
    const unsigned ks0 = k0, ks1 = k1, ks2 = k0 ^ k1 ^ 0x1BD11BDAu;
    x0 += ks0; x1 += ks1;
#define TF_ROT(v, r) (((v) << (r)) | ((v) >> (32 - (r))))
#define TF_R(r) { x0 += x1; x1 = TF_ROT(x1, r); x1 ^= x0; }
    TF_R(13) TF_R(15) TF_R(26) TF_R(6)   x0 += ks1; x1 += ks2 + 1u;
    TF_R(17) TF_R(29) TF_R(16) TF_R(24)  x0 += ks2; x1 += ks0 + 2u;
    TF_R(13) TF_R(15) TF_R(26) TF_R(6)   x0 += ks0; x1 += ks1 + 3u;
    TF_R(17) TF_R(29) TF_R(16) TF_R(24)  x0 += ks1; x1 += ks2 + 4u;
    TF_R(13) TF_R(15) TF_R(26) TF_R(6)   x0 += ks2; x1 += ks0 + 5u;
#undef TF_R
#undef TF_ROT
}

// ---------------------------------------------------------------- kernels

// per-(b,c) mean/std over L (x is [B,L,C])
__global__ __launch_bounds__(256) void revin_stats(const float* __restrict__ x,
                                                   float* __restrict__ meanB,
                                                   float* __restrict__ stdB) {
    int b = blockIdx.x;
    int c = blockIdx.y * 256 + threadIdx.x;
    const float* xp = x + (size_t)b * L_ * C_ + c;
    float s = 0.f, ss = 0.f;
    for (int l = 0; l < L_; ++l) {
        float v = xp[(size_t)l * C_];
        s += v; ss += v * v;
    }
    float m = s * (1.0f / L_);
    float var = ss * (1.0f / L_) - m * m;
    meanB[b * C_ + c] = m;
    stdB[b * C_ + c]  = sqrtf(var + 1e-5f);
}

// x [B,L,C] -> xt [B,C,L] with RevIN applied
__global__ __launch_bounds__(256) void transpose_revin(const float* __restrict__ x,
                                                       const float* __restrict__ meanB,
                                                       const float* __restrict__ stdB,
                                                       const float* __restrict__ rw,
                                                       const float* __restrict__ rb,
                                                       float* __restrict__ xt) {
    __shared__ float tile[32][33];
    int b = blockIdx.x, l0 = blockIdx.y * 32, c0 = blockIdx.z * 32;
    int tx = threadIdx.x, ty = threadIdx.y;
    for (int i = ty; i < 32; i += 8) {
        int l = l0 + i, c = c0 + tx;
        float v = x[((size_t)b * L_ + l) * C_ + c];
        v = (v - meanB[b * C_ + c]) / stdB[b * C_ + c] * rw[c] + rb[c];
        tile[i][tx] = v;
    }
    __syncthreads();
    for (int i = ty; i < 32; i += 8) {
        int c = c0 + i, l = l0 + tx;
        xt[((size_t)b * C_ + c) * L_ + l] = tile[tx][i];
    }
}

// plain per-batch 512x512 transpose
__global__ __launch_bounds__(256) void transpose_b(const float* __restrict__ in,
                                                   float* __restrict__ out) {
    __shared__ float tile[32][33];
    int b = blockIdx.x, r0 = blockIdx.y * 32, c0 = blockIdx.z * 32;
    int tx = threadIdx.x, ty = threadIdx.y;
    for (int i = ty; i < 32; i += 8)
        tile[i][tx] = in[((size_t)b * 512 + r0 + i) * 512 + c0 + tx];
    __syncthreads();
    for (int i = ty; i < 32; i += 8)
        out[((size_t)b * 512 + c0 + i) * 512 + r0 + tx] = tile[tx][i];
}

// tiled fp32 GEMM: C[M,N] = epi(A[M,K] @ B[K,N] + bias)
// EPI: 0=store  1=relu-store  2=gelu-store  3=C+=gelu(acc+bias)  4=C+=acc+bias
template <int EPI>
__global__ __launch_bounds__(256) void gemm_f32(const float* __restrict__ A,
                                                const float* __restrict__ Bm,
                                                const float* __restrict__ bias,
                                                float* __restrict__ Cm,
                                                int M, int N, int K) {
    __shared__ float As[16][64];  // [k][m]
    __shared__ float Bs[16][64];  // [k][n]
    int tid = threadIdx.x;
    int tx = tid & 15, ty = tid >> 4;
    int m0 = blockIdx.y * 64, n0 = blockIdx.x * 64;
    float acc[4][4] = {};
    for (int k0 = 0; k0 < K; k0 += 16) {
        {   // A tile: 64 rows x 16 k
            int r = tid >> 2;
            int cc = (tid & 3) * 4;
            int gm = m0 + r;
            float4 v = make_float4(0.f, 0.f, 0.f, 0.f);
            if (gm < M) v = *(const float4*)(A + (size_t)gm * K + k0 + cc);
            As[cc + 0][r] = v.x; As[cc + 1][r] = v.y;
            As[cc + 2][r] = v.z; As[cc + 3][r] = v.w;
        }
        {   // B tile: 16 k x 64 n
            int r = tid >> 4;
            int cc = (tid & 15) * 4;
            float4 v = *(const float4*)(Bm + (size_t)(k0 + r) * N + n0 + cc);
            *(float4*)&Bs[r][cc] = v;
        }
        __syncthreads();
        #pragma unroll
        for (int kk = 0; kk < 16; ++kk) {
            float4 a4 = *(const float4*)&As[kk][ty * 4];
            float4 b4 = *(const float4*)&Bs[kk][tx * 4];
            float av[4] = {a4.x, a4.y, a4.z, a4.w};
            float bv[4] = {b4.x, b4.y, b4.z, b4.w};
            #pragma unroll
            for (int i = 0; i < 4; ++i)
                #pragma unroll
                for (int j = 0; j < 4; ++j)
                    acc[i][j] += av[i] * bv[j];
        }
        __syncthreads();
    }
    int gn = n0 + tx * 4;
    float4 b4 = *(const float4*)(bias + gn);
    float bb[4] = {b4.x, b4.y, b4.z, b4.w};
    #pragma unroll
    for (int i = 0; i < 4; ++i) {
        int gm = m0 + ty * 4 + i;
        if (gm >= M) break;
        float v[4];
        #pragma unroll
        for (int j = 0; j < 4; ++j) {
            float t = acc[i][j] + bb[j];
            if (EPI == 1) t = fmaxf(t, 0.f);
            if (EPI == 2 || EPI == 3) t = gelu_f(t);
            v[j] = t;
        }
        float* cp = Cm + (size_t)gm * N + gn;
        if (EPI == 3 || EPI == 4) {
            float4 old = *(float4*)cp;
            v[0] += old.x; v[1] += old.y; v[2] += old.z; v[3] += old.w;
        }
        *(float4*)cp = make_float4(v[0], v[1], v[2], v[3]);
    }
}

// layernorm over rows of width 512, per-column affine
__global__ __launch_bounds__(256) void ln_rows(const float* __restrict__ in,
                                               float* __restrict__ out,
                                               const float* __restrict__ g,
                                               const float* __restrict__ b) {
    int row = blockIdx.x, tid = threadIdx.x;
    float2 v = ((const float2*)(in + (size_t)row * 512))[tid];
    float s = v.x + v.y, ss = v.x * v.x + v.y * v.y;
    block_sum2_256(s, ss);
    float mean = s * (1.0f / 512.0f);
    float var  = ss * (1.0f / 512.0f) - mean * mean;
    float rstd = rsqrtf(var + 1e-5f);
    float2 gv = ((const float2*)g)[tid];
    float2 bv = ((const float2*)b)[tid];
    float2 o;
    o.x = (v.x - mean) * rstd * gv.x + bv.x;
    o.y = (v.y - mean) * rstd * gv.y + bv.y;
    ((float2*)(out + (size_t)row * 512))[tid] = o;
}

// normalize 16 rows of 512 (cluster embeds -> cn)
__global__ __launch_bounds__(256) void normalize_rows16(const float* __restrict__ ce,
                                                        float* __restrict__ cn) {
    int k = blockIdx.x, tid = threadIdx.x;
    float2 v = ((const float2*)(ce + (size_t)k * 512))[tid];
    float ss = v.x * v.x + v.y * v.y, dummy = 0.f;
    block_sum2_256(ss, dummy);
    float inv = 1.0f / fmaxf(sqrtf(ss), 1e-12f);
    float2 o; o.x = v.x * inv; o.y = v.y * inv;
    ((float2*)(cn + (size_t)k * 512))[tid] = o;
}

// p[b,c,k] = softmax_k( cos(h[b,c,:], cn[k,:]) ); block handles 16 rows
__global__ __launch_bounds__(256) void routing_kernel(const float* __restrict__ h,
                                                      const float* __restrict__ cn,
                                                      float* __restrict__ p) {
    int tid = threadIdx.x;
    int r = tid >> 4, k = tid & 15;
    int row = blockIdx.x * 16 + r;
    const float4* hp = (const float4*)(h + (size_t)row * 512);
    const float4* ck = (const float4*)(cn + (size_t)k * 512);
    float ss = 0.f;
    #pragma unroll
    for (int j = k * 8; j < k * 8 + 8; ++j) {
        float4 v = hp[j];
        ss += v.x * v.x + v.y * v.y + v.z * v.z + v.w * v.w;
    }
    #pragma unroll
    for (int off = 8; off; off >>= 1) ss += __shfl_xor(ss, off, 16);
    float inv = 1.0f / fmaxf(sqrtf(ss), 1e-12f);
    float d = 0.f;
    for (int j = 0; j < 128; ++j) {
        float4 a = hp[j], b = ck[j];
        d += a.x * b.x + a.y * b.y + a.z * b.z + a.w * b.w;
    }
    d *= inv;
    float mx = d;
    #pragma unroll
    for (int off = 8; off; off >>= 1) mx = fmaxf(mx, __shfl_xor(mx, off, 16));
    float e = expf(d - mx);
    float s = e;
    #pragma unroll
    for (int off = 8; off; off >>= 1) s += __shfl_xor(s, off, 16);
    p[(size_t)row * 16 + k] = e / s;
}

// M = (jax uniform < p), threefry2x32 key (0,42), pairs (i, HALF+i)
__global__ __launch_bounds__(256) void bernoulli_kernel(const float* __restrict__ p,
                                                        float* __restrict__ Mout) {
    const int HALF = (B_ * C_ * K_) / 2;  // 131072
    int i = blockIdx.x * 256 + threadIdx.x;
    if (i >= HALF) return;
    unsigned x0 = (unsigned)i, x1 = (unsigned)(HALF + i);
    threefry2x32(0u, 42u, x0, x1);
    float u0 = __uint_as_float((x0 >> 9) | 0x3f800000u) - 1.0f;
    float u1 = __uint_as_float((x1 >> 9) | 0x3f800000u) - 1.0f;
    Mout[i]        = (u0 < p[i])        ? 1.0f : 0.0f;
    Mout[HALF + i] = (u1 < p[HALF + i]) ? 1.0f : 0.0f;
}

// am[b,k,c] = exp(dot(Q[k], Kk[b,c]) / sqrt(H)) * M[b,c,k]; 16 rows per block
__global__ __launch_bounds__(256) void attn_scores(const float* __restrict__ Kk,
                                                   const float* __restrict__ Q,
                                                   const float* __restrict__ Mmask,
                                                   float* __restrict__ am) {
    int tid = threadIdx.x;
    int k = tid >> 4, r = tid & 15;
    int row = blockIdx.x * 16 + r;           // row = b*C + c
    int b = row >> 9, c = row & 511;
    const float4* kp = (const float4*)(Kk + (size_t)row * 512);
    const float4* qp = (const float4*)(Q + (size_t)k * 512);
    float d = 0.f;
    for (int j = 0; j < 128; ++j) {
        float4 a = kp[j], q = qp[j];
        d += a.x * q.x + a.y * q.y + a.z * q.z + a.w * q.w;
    }
    d *= 0.044194173824159216f;  // 1/sqrt(512)
    float m = Mmask[(size_t)row * 16 + k];
    am[((size_t)b * 16 + k) * 512 + c] = expf(d) * m;
}

// recip[b,k] = 1 / sum_c am[b,k,c]
__global__ __launch_bounds__(256) void row_recip(const float* __restrict__ am,
                                                 float* __restrict__ recip) {
    int rk = blockIdx.x, tid = threadIdx.x;
    float2 v = ((const float2*)(am + (size_t)rk * 512))[tid];
    float s = v.x + v.y, dummy = 0.f;
    block_sum2_256(s, dummy);
    if (tid == 0) recip[rk] = 1.0f / s;
}

// Cc[b,k,h] = sum_c aw[b,k,c] * V[b,c,h]
__global__ __launch_bounds__(256) void cc_kernel(const float* __restrict__ am,
                                                 const float* __restrict__ recip,
                                                 const float* __restrict__ V,
                                                 float* __restrict__ Cc) {
    __shared__ float awsS[16 * 512];
    int b = blockIdx.x;
    int h = blockIdx.y * 256 + threadIdx.x;
    for (int idx = threadIdx.x; idx < 16 * 512; idx += 256) {
        int kk = idx >> 9;
        awsS[idx] = am[(size_t)b * 16 * 512 + idx] * recip[b * 16 + kk];
    }
    __syncthreads();
    float acc[16] = {};
    const float* vp = V + (size_t)b * 512 * 512 + h;
    for (int cc = 0; cc < 512; ++cc) {
        float v = vp[(size_t)cc * 512];
        #pragma unroll
        for (int kk = 0; kk < 16; ++kk) acc[kk] += awsS[kk * 512 + cc] * v;
    }
    #pragma unroll
    for (int kk = 0; kk < 16; ++kk)
        Cc[((size_t)b * 16 + kk) * 512 + h] = acc[kk];
}

// ce_new = mean over b of Cc
__global__ __launch_bounds__(256) void cc_mean(const float* __restrict__ Cc,
                                               float* __restrict__ ce_new) {
    int idx = blockIdx.x * 256 + threadIdx.x;  // < 8192
    float s = 0.f;
    for (int b = 0; b < B_; ++b) s += Cc[(size_t)b * (K_ * H_) + idx];
    ce_new[idx] = s * (1.0f / B_);
}

// theta[row,h] = sum_k p[row,k] * ce_new[k,h]
__global__ __launch_bounds__(256) void theta_kernel(const float* __restrict__ p,
                                                    const float* __restrict__ ce,
                                                    float* __restrict__ theta) {
    int row = blockIdx.x, tid = threadIdx.x;
    float pk[16];
    #pragma unroll
    for (int k = 0; k < 16; ++k) pk[k] = p[(size_t)row * 16 + k];
    for (int h = tid; h < 512; h += 256) {
        float s = 0.f;
        #pragma unroll
        for (int k = 0; k < 16; ++k) s += pk[k] * ce[k * 512 + h];
        theta[(size_t)row * 512 + h] = s;
    }
}

// per-channel expert projection + output transpose + RevIN denorm
__global__ __launch_bounds__(256) void out_proj(const float* __restrict__ Hm,
                                                const float* __restrict__ theta,
                                                const float* __restrict__ out_w,
                                                const float* __restrict__ out_b,
                                                const float* __restrict__ rev_w,
                                                const float* __restrict__ rev_b,
                                                const float* __restrict__ meanB,
                                                const float* __restrict__ stdB,
                                                float* __restrict__ out) {
    int c = blockIdx.x, tid = threadIdx.x;
    __shared__ float wS[32 * 96];
    __shared__ float gS[32 * 33];
    int b_own = tid >> 3;
    int pbase = (tid & 7) * 12;
    float acc[12];
    #pragma unroll
    for (int j = 0; j < 12; ++j) acc[j] = out_b[(size_t)c * 96 + pbase + j];
    const size_t wbase = (size_t)c * 512 * 96;
    for (int h0 = 0; h0 < 512; h0 += 32) {
        __syncthreads();
        for (int idx = tid; idx < 3072; idx += 256)
            wS[idx] = out_w[wbase + (size_t)h0 * 96 + idx];
        for (int idx = tid; idx < 1024; idx += 256) {
            int bb = idx >> 5, hh = idx & 31;
            size_t off = ((size_t)bb * 512 + c) * 512 + h0 + hh;
            gS[bb * 33 + hh] = Hm[off] * theta[off];
        }
        __syncthreads();
        #pragma unroll 4
        for (int hh = 0; hh < 32; ++hh) {
            float gb = gS[b_own * 33 + hh];
            #pragma unroll
            for (int j = 0; j < 12; ++j) acc[j] += gb * wS[hh * 96 + pbase + j];
        }
    }
    float inv_rw = 1.0f / (rev_w[c] + 1e-10f);
    float rb = rev_b[c];
    float mn = meanB[b_own * C_ + c];
    float sd = stdB[b_own * C_ + c];
    #pragma unroll
    for (int j = 0; j < 12; ++j) {
        float y = (acc[j] - rb) * inv_rw * sd + mn;
        out[((size_t)b_own * 96 + (pbase + j)) * 512 + c] = y;
    }
}

// ---------------------------------------------------------------- launch

extern "C" void kernel_launch(void* const* d_in, const int* in_sizes, int n_in,
                              void* d_out, int out_size, void* d_ws, size_t ws_size,
                              hipStream_t stream) {
    const float* x        = (const float*)d_in[0];
    const float* rev_w    = (const float*)d_in[1];
    const float* rev_b    = (const float*)d_in[2];
    const float* mlp_w1   = (const float*)d_in[3];
    const float* mlp_b1   = (const float*)d_in[4];
    const float* mlp_w2   = (const float*)d_in[5];
    const float* mlp_b2   = (const float*)d_in[6];
    const float* clu_emb  = (const float*)d_in[7];
    const float* wq       = (const float*)d_in[8];
    const float* bq       = (const float*)d_in[9];
    const float* wk       = (const float*)d_in[10];
    const float* bk       = (const float*)d_in[11];
    const float* wv       = (const float*)d_in[12];
    const float* bv       = (const float*)d_in[13];
    const float* ts_ln_g  = (const float*)d_in[14];
    const float* ts_ln_b  = (const float*)d_in[15];
    const float* ts_w     = (const float*)d_in[16];
    const float* ts_b     = (const float*)d_in[17];
    const float* ch_ln_g  = (const float*)d_in[18];
    const float* ch_ln_b  = (const float*)d_in[19];
    const float* ch_w1    = (const float*)d_in[20];
    const float* ch_b1    = (const float*)d_in[21];
    const float* ch_w2    = (const float*)d_in[22];
    const float* ch_b2    = (const float*)d_in[23];
    const float* out_w    = (const float*)d_in[24];
    const float* out_b    = (const float*)d_in[25];

    float* f = (float*)d_ws;
    const size_t SLOT = (size_t)(B_ * C_) * H_;   // 8388608 floats
    float* S0 = f;
    float* S1 = f + SLOT;
    float* S2 = f + 2 * SLOT;
    float* S3 = f + 3 * SLOT;
    float* sm = f + 4 * SLOT;
    float* meanB  = sm; sm += B_ * C_;
    float* stdB   = sm; sm += B_ * C_;
    float* pbuf   = sm; sm += B_ * C_ * K_;
    float* Mbuf   = sm; sm += B_ * C_ * K_;
    float* ambuf  = sm; sm += B_ * K_ * C_;
    float* recips = sm; sm += B_ * K_;
    float* Ccbuf  = sm; sm += B_ * K_ * H_;
    float* cebuf  = sm; sm += K_ * H_;
    float* cnbuf  = sm; sm += K_ * H_;
    float* Qbuf   = sm; sm += K_ * H_;

    const int Mrows = B_ * C_;  // 16384
    dim3 gemm_grid(H_ / 64, Mrows / 64);   // (8, 256)
    dim3 t_grid(B_, 16, 16);
    dim3 t_blk(32, 8);

    // 1-2: RevIN stats + normalized transpose -> xt (S0)
    revin_stats<<<dim3(B_, C_ / 256), 256, 0, stream>>>(x, meanB, stdB);
    transpose_revin<<<t_grid, t_blk, 0, stream>>>(x, meanB, stdB, rev_w, rev_b, S0);
    // 3-4: channel MLP -> h (S0)
    gemm_f32<1><<<gemm_grid, 256, 0, stream>>>(S0, mlp_w1, mlp_b1, S1, Mrows, H_, L_);
    gemm_f32<0><<<gemm_grid, 256, 0, stream>>>(S1, mlp_w2, mlp_b2, S0, Mrows, H_, H_);
    float* hbuf = S0;
    // 5-7: routing p + bernoulli mask
    normalize_rows16<<<K_, 256, 0, stream>>>(clu_emb, cnbuf);
    routing_kernel<<<Mrows / 16, 256, 0, stream>>>(hbuf, cnbuf, pbuf);
    bernoulli_kernel<<<(B_ * C_ * K_) / 2 / 256, 256, 0, stream>>>(pbuf, Mbuf);
    // 8: Q (tiny GEMM, M=16)
    gemm_f32<0><<<dim3(H_ / 64, 1), 256, 0, stream>>>(clu_emb, wq, bq, Qbuf, K_, H_, H_);
    // 9-10: Kk (S1), V (S2)
    gemm_f32<0><<<gemm_grid, 256, 0, stream>>>(hbuf, wk, bk, S1, Mrows, H_, H_);
    gemm_f32<0><<<gemm_grid, 256, 0, stream>>>(hbuf, wv, bv, S2, Mrows, H_, H_);
    // 11-14: masked attention -> ce_new
    attn_scores<<<Mrows / 16, 256, 0, stream>>>(S1, Qbuf, Mbuf, ambuf);
    row_recip<<<B_ * K_, 256, 0, stream>>>(ambuf, recips);
    cc_kernel<<<dim3(B_, 2), 256, 0, stream>>>(ambuf, recips, S2, Ccbuf);
    cc_mean<<<(K_ * H_) / 256, 256, 0, stream>>>(Ccbuf, cebuf);
    // 15: theta (S2; V dead)
    theta_kernel<<<Mrows, 256, 0, stream>>>(pbuf, cebuf, S2);
    // 16: u (S3) = transpose(h)   [B,C,H] -> [B,H,C]
    transpose_b<<<t_grid, t_blk, 0, stream>>>(hbuf, S3);
    // 17: mixer x4 in [B,H,C] layout (transposes cancel); tmpA=S0, tmpB=S1
    for (int it = 0; it < NB_; ++it) {
        ln_rows<<<B_ * H_, 256, 0, stream>>>(S3, S0, ts_ln_g, ts_ln_b);
        gemm_f32<3><<<gemm_grid, 256, 0, stream>>>(S0, ts_w, ts_b, S3, Mrows, C_, C_);
        ln_rows<<<B_ * H_, 256, 0, stream>>>(S3, S0, ch_ln_g, ch_ln_b);
        gemm_f32<2><<<gemm_grid, 256, 0, stream>>>(S0, ch_w1, ch_b1, S1, Mrows, H_, C_);
        gemm_f32<4><<<gemm_grid, 256, 0, stream>>>(S1, ch_w2, ch_b2, S3, Mrows, C_, H_);
    }
    // 18: Hm (S0) = transpose(u)   [B,H,C] -> [B,C,H]
    transpose_b<<<t_grid, t_blk, 0, stream>>>(S3, S0);
    // 19: expert projection + denorm -> out [B,P,C]
    out_proj<<<C_, 256, 0, stream>>>(S0, S2, out_w, out_b, rev_w, rev_b,
                                     meanB, stdB, (float*)d_out);
}

// Round 2
// 1171.345 us; speedup vs baseline: 2.3663x; 2.3663x over previous
//
#include <hip/hip_runtime.h>
#include <math.h>

#define B_  32
#define L_  512
#define C_  512
#define H_  512
#define K_  16
#define P_  96
#define NB_ 4

typedef unsigned short u16;
typedef __attribute__((ext_vector_type(8))) __bf16 bf16x8;
typedef __attribute__((ext_vector_type(4))) float f32x4;

// ---------------------------------------------------------------- helpers

__device__ __forceinline__ float gelu_f(float x) {
    return 0.5f * x * (1.0f + erff(x * 0.70710678118654752440f));
}

__device__ __forceinline__ u16 f2bf(float f) {
    union { float f; unsigned u; } v; v.f = f;
    unsigned r = v.u + 0x7fffu + ((v.u >> 16) & 1u);   // RNE
    return (u16)(r >> 16);
}
__device__ __forceinline__ float bf2f(u16 h) {
    union { unsigned u; float f; } v; v.u = ((unsigned)h) << 16;
    return v.f;
}

// block(256) dual sum reduce; call at most once per kernel
__device__ __forceinline__ void block_sum2_256(float& a, float& b) {
    __shared__ float la[4], lb[4];
    #pragma unroll
    for (int off = 32; off; off >>= 1) {
        a += __shfl_down(a, off);
        b += __shfl_down(b, off);
    }
    int wid = threadIdx.x >> 6;
    if ((threadIdx.x & 63) == 0) { la[wid] = a; lb[wid] = b; }
    __syncthreads();
    a = la[0] + la[1] + la[2] + la[3];
    b = lb[0] + lb[1] + lb[2] + lb[3];
}

// JAX threefry2x32, key = (k0,k1)
__device__ __forceinline__ void threefry2x32(unsigned k0, unsigned k1,
                                             unsigned& x0, unsigned& x1) {
    const unsigned ks0 = k0, ks1 = k1, ks2 = k0 ^ k1 ^ 0x1BD11BDAu;
    x0 += ks0; x1 += ks1;
#define TF_ROT(v, r) (((v) << (r)) | ((v) >> (32 - (r))))
#define TF_R(r) { x0 += x1; x1 = TF_ROT(x1, r); x1 ^= x0; }
    TF_R(13) TF_R(15) TF_R(26) TF_R(6)   x0 += ks1; x1 += ks2 + 1u;
    TF_R(17) TF_R(29) TF_R(16) TF_R(24)  x0 += ks2; x1 += ks0 + 2u;
    TF_R(13) TF_R(15) TF_R(26) TF_R(6)   x0 += ks0; x1 += ks1 + 3u;
    TF_R(17) TF_R(29) TF_R(16) TF_R(24)  x0 += ks1; x1 += ks2 + 4u;
    TF_R(13) TF_R(15) TF_R(26) TF_R(6)   x0 += ks2; x1 += ks0 + 5u;
#undef TF_R
#undef TF_ROT
}

#define GLL16(g, l) __builtin_amdgcn_global_load_lds( \
    (const __attribute__((address_space(1))) void*)(g), \
    (__attribute__((address_space(3))) void*)(l), 16, 0, 0)

// ---------------------------------------------------------------- kernels

// per-(b,c) mean/std over L (x is [B,L,C])
__global__ __launch_bounds__(256) void revin_stats(const float* __restrict__ x,
                                                   float* __restrict__ meanB,
                                                   float* __restrict__ stdB) {
    int b = blockIdx.x;
    int c = blockIdx.y * 256 + threadIdx.x;
    const float* xp = x + (size_t)b * L_ * C_ + c;
    float s = 0.f, ss = 0.f;
    for (int l = 0; l < L_; ++l) {
        float v = xp[(size_t)l * C_];
        s += v; ss += v * v;
    }
    float m = s * (1.0f / L_);
    float var = ss * (1.0f / L_) - m * m;
    meanB[b * C_ + c] = m;
    stdB[b * C_ + c]  = sqrtf(var + 1e-5f);
}

// x [B,L,C] -> xt bf16 [B,C,L] with RevIN applied
__global__ __launch_bounds__(256) void transpose_revin(const float* __restrict__ x,
                                                       const float* __restrict__ meanB,
                                                       const float* __restrict__ stdB,
                                                       const float* __restrict__ rw,
                                                       const float* __restrict__ rb,
                                                       u16* __restrict__ xt) {
    __shared__ float tile[32][33];
    int b = blockIdx.x, l0 = blockIdx.y * 32, c0 = blockIdx.z * 32;
    int tx = threadIdx.x, ty = threadIdx.y;
    for (int i = ty; i < 32; i += 8) {
        int l = l0 + i, c = c0 + tx;
        float v = x[((size_t)b * L_ + l) * C_ + c];
        v = (v - meanB[b * C_ + c]) / stdB[b * C_ + c] * rw[c] + rb[c];
        tile[i][tx] = v;
    }
    __syncthreads();
    for (int i = ty; i < 32; i += 8) {
        int c = c0 + i, l = l0 + tx;
        xt[((size_t)b * C_ + c) * L_ + l] = f2bf(tile[tx][i]);
    }
}

// plain per-batch 512x512 fp32 transpose
__global__ __launch_bounds__(256) void transpose_b(const float* __restrict__ in,
                                                   float* __restrict__ out) {
    __shared__ float tile[32][33];
    int b = blockIdx.x, r0 = blockIdx.y * 32, c0 = blockIdx.z * 32;
    int tx = threadIdx.x, ty = threadIdx.y;
    for (int i = ty; i < 32; i += 8)
        tile[i][tx] = in[((size_t)b * 512 + r0 + i) * 512 + c0 + tx];
    __syncthreads();
    for (int i = ty; i < 32; i += 8)
        out[((size_t)b * 512 + c0 + i) * 512 + r0 + tx] = tile[tx][i];
}

// 7 weight matrices [512][512] f32 -> transposed bf16 [512][512]
struct WPtrs { const float* src[7]; u16* dst[7]; };
__global__ __launch_bounds__(256) void convert_w(WPtrs wp) {
    __shared__ float tile[32][33];
    int wi = blockIdx.z;
    const float* src = wp.src[wi];
    u16* dst = wp.dst[wi];
    int r0 = blockIdx.y * 32, c0 = blockIdx.x * 32;
    int tx = threadIdx.x, ty = threadIdx.y;
    for (int i = ty; i < 32; i += 8)
        tile[i][tx] = src[(size_t)(r0 + i) * 512 + c0 + tx];
    __syncthreads();
    for (int i = ty; i < 32; i += 8)
        dst[(size_t)(c0 + i) * 512 + r0 + tx] = f2bf(tile[tx][i]);
}

// bf16 MFMA GEMM, m97 structure: 128x128 tile, BK=32, 256 thr (4 waves 2x2).
// A [M][K] bf16, Bt [N][K] bf16 (pre-transposed). acc fp32.
// EPI: 0 store f32 | 1 relu->bf16 | 2 gelu->bf16 | 3 f32 += gelu(acc+b)
//      4 f32 += acc+b | 5 store f32 AND bf16 | 6 store bf16
template <int EPI>
__global__ __launch_bounds__(256) void gemm_bf16(const u16* __restrict__ A,
                                                 const u16* __restrict__ Bt,
                                                 const float* __restrict__ bias,
                                                 float* __restrict__ C32,
                                                 u16* __restrict__ C16,
                                                 int M, int N, int K) {
    __shared__ u16 As[128 * 32];
    __shared__ u16 Bs[128 * 32];
    int tid = threadIdx.x;
    int m0 = blockIdx.y * 128, n0 = blockIdx.x * 128;
    int lane = tid & 63, wave = tid >> 6;
    int wm = wave >> 1, wn = wave & 1;
    int col = lane & 15, quad = lane >> 4;
    int koff = quad * 8;

    int qa0 = tid, qa1 = tid + 256;
    const u16* Ag0 = A + (size_t)(m0 + (qa0 >> 2)) * K + (qa0 & 3) * 8;
    const u16* Ag1 = A + (size_t)(m0 + (qa1 >> 2)) * K + (qa1 & 3) * 8;
    const u16* Bg0 = Bt + (size_t)(n0 + (qa0 >> 2)) * K + (qa0 & 3) * 8;
    const u16* Bg1 = Bt + (size_t)(n0 + (qa1 >> 2)) * K + (qa1 & 3) * 8;
    u16* Al0 = &As[qa0 * 8];
    u16* Al1 = &As[qa1 * 8];
    u16* Bl0 = &Bs[qa0 * 8];
    u16* Bl1 = &Bs[qa1 * 8];

    f32x4 acc[4][4];
    #pragma unroll
    for (int i = 0; i < 4; ++i)
        #pragma unroll
        for (int j = 0; j < 4; ++j)
            acc[i][j] = (f32x4){0.f, 0.f, 0.f, 0.f};

    for (int k0 = 0; k0 < K; k0 += 32) {
        GLL16(Ag0 + k0, Al0);
        GLL16(Ag1 + k0, Al1);
        GLL16(Bg0 + k0, Bl0);
        GLL16(Bg1 + k0, Bl1);
        __syncthreads();
        bf16x8 af[4], bfr[4];
        #pragma unroll
        for (int mt = 0; mt < 4; ++mt)
            af[mt] = *(const bf16x8*)&As[(wm * 64 + mt * 16 + col) * 32 + koff];
        #pragma unroll
        for (int nt = 0; nt < 4; ++nt)
            bfr[nt] = *(const bf16x8*)&Bs[(wn * 64 + nt * 16 + col) * 32 + koff];
        #pragma unroll
        for (int mt = 0; mt < 4; ++mt)
            #pragma unroll
            for (int nt = 0; nt < 4; ++nt)
                acc[mt][nt] = __builtin_amdgcn_mfma_f32_16x16x32_bf16(
                    af[mt], bfr[nt], acc[mt][nt], 0, 0, 0);
        __syncthreads();
    }

    float bb[4];
    #pragma unroll
    for (int nt = 0; nt < 4; ++nt) bb[nt] = bias[n0 + wn * 64 + nt * 16 + col];
    #pragma unroll
    for (int mt = 0; mt < 4; ++mt) {
        int mbase = m0 + wm * 64 + mt * 16 + quad * 4;
        #pragma unroll
        for (int r = 0; r < 4; ++r) {
            size_t rowoff = (size_t)(mbase + r) * N;
            #pragma unroll
            for (int nt = 0; nt < 4; ++nt) {
                int gn = n0 + wn * 64 + nt * 16 + col;
                float t = acc[mt][nt][r] + bb[nt];
                if (EPI == 1) t = fmaxf(t, 0.f);
                if (EPI == 2 || EPI == 3) t = gelu_f(t);
                if (EPI == 0) {
                    C32[rowoff + gn] = t;
                } else if (EPI == 1 || EPI == 2 || EPI == 6) {
                    C16[rowoff + gn] = f2bf(t);
                } else if (EPI == 3 || EPI == 4) {
                    C32[rowoff + gn] += t;
                } else if (EPI == 5) {
                    C32[rowoff + gn] = t;
                    C16[rowoff + gn] = f2bf(t);
                }
            }
        }
    }
}

// fp32 tiled GEMM (only for tiny Q = clu_emb @ wq + bq, M=16)
__global__ __launch_bounds__(256) void gemm_f32(const float* __restrict__ A,
                                                const float* __restrict__ Bm,
                                                const float* __restrict__ bias,
                                                float* __restrict__ Cm,
                                                int M, int N, int K) {
    __shared__ float As[16][64];
    __shared__ float Bs[16][64];
    int tid = threadIdx.x;
    int tx = tid & 15, ty = tid >> 4;
    int m0 = blockIdx.y * 64, n0 = blockIdx.x * 64;
    float acc[4][4] = {};
    for (int k0 = 0; k0 < K; k0 += 16) {
        {
            int r = tid >> 2, cc = (tid & 3) * 4, gm = m0 + r;
            float4 v = make_float4(0.f, 0.f, 0.f, 0.f);
            if (gm < M) v = *(const float4*)(A + (size_t)gm * K + k0 + cc);
            As[cc + 0][r] = v.x; As[cc + 1][r] = v.y;
            As[cc + 2][r] = v.z; As[cc + 3][r] = v.w;
        }
        {
            int r = tid >> 4, cc = (tid & 15) * 4;
            *(float4*)&Bs[r][cc] = *(const float4*)(Bm + (size_t)(k0 + r) * N + n0 + cc);
        }
        __syncthreads();
        #pragma unroll
        for (int kk = 0; kk < 16; ++kk) {
            float4 a4 = *(const float4*)&As[kk][ty * 4];
            float4 b4 = *(const float4*)&Bs[kk][tx * 4];
            float av[4] = {a4.x, a4.y, a4.z, a4.w};
            float bv[4] = {b4.x, b4.y, b4.z, b4.w};
            #pragma unroll
            for (int i = 0; i < 4; ++i)
                #pragma unroll
                for (int j = 0; j < 4; ++j)
                    acc[i][j] += av[i] * bv[j];
        }
        __syncthreads();
    }
    int gn = n0 + tx * 4;
    float4 b4 = *(const float4*)(bias + gn);
    float bb[4] = {b4.x, b4.y, b4.z, b4.w};
    #pragma unroll
    for (int i = 0; i < 4; ++i) {
        int gm = m0 + ty * 4 + i;
        if (gm >= M) break;
        float* cp = Cm + (size_t)gm * N + gn;
        *(float4*)cp = make_float4(acc[i][0] + bb[0], acc[i][1] + bb[1],
                                   acc[i][2] + bb[2], acc[i][3] + bb[3]);
    }
}

// layernorm over fp32 rows of 512 -> bf16 out
__global__ __launch_bounds__(256) void ln_rows(const float* __restrict__ in,
                                               u16* __restrict__ out,
                                               const float* __restrict__ g,
                                               const float* __restrict__ b) {
    int row = blockIdx.x, tid = threadIdx.x;
    float2 v = ((const float2*)(in + (size_t)row * 512))[tid];
    float s = v.x + v.y, ss = v.x * v.x + v.y * v.y;
    block_sum2_256(s, ss);
    float mean = s * (1.0f / 512.0f);
    float var  = ss * (1.0f / 512.0f) - mean * mean;
    float rstd = rsqrtf(var + 1e-5f);
    float2 gv = ((const float2*)g)[tid];
    float2 bv = ((const float2*)b)[tid];
    ushort2 o;
    o.x = f2bf((v.x - mean) * rstd * gv.x + bv.x);
    o.y = f2bf((v.y - mean) * rstd * gv.y + bv.y);
    ((ushort2*)(out + (size_t)row * 512))[tid] = o;
}

// normalize 16 rows of 512 (cluster embeds -> cn)
__global__ __launch_bounds__(256) void normalize_rows16(const float* __restrict__ ce,
                                                        float* __restrict__ cn) {
    int k = blockIdx.x, tid = threadIdx.x;
    float2 v = ((const float2*)(ce + (size_t)k * 512))[tid];
    float ss = v.x * v.x + v.y * v.y, dummy = 0.f;
    block_sum2_256(ss, dummy);
    float inv = 1.0f / fmaxf(sqrtf(ss), 1e-12f);
    float2 o; o.x = v.x * inv; o.y = v.y * inv;
    ((float2*)(cn + (size_t)k * 512))[tid] = o;
}

// p[b,c,k] = softmax_k( cos(h[b,c,:], cn[k,:]) ); block handles 16 rows
__global__ __launch_bounds__(256) void routing_kernel(const float* __restrict__ h,
                                                      const float* __restrict__ cn,
                                                      float* __restrict__ p) {
    int tid = threadIdx.x;
    int r = tid >> 4, k = tid & 15;
    int row = blockIdx.x * 16 + r;
    const float4* hp = (const float4*)(h + (size_t)row * 512);
    const float4* ck = (const float4*)(cn + (size_t)k * 512);
    float ss = 0.f;
    #pragma unroll
    for (int j = k * 8; j < k * 8 + 8; ++j) {
        float4 v = hp[j];
        ss += v.x * v.x + v.y * v.y + v.z * v.z + v.w * v.w;
    }
    #pragma unroll
    for (int off = 8; off; off >>= 1) ss += __shfl_xor(ss, off, 16);
    float inv = 1.0f / fmaxf(sqrtf(ss), 1e-12f);
    float d = 0.f;
    for (int j = 0; j < 128; ++j) {
        float4 a = hp[j], b = ck[j];
        d += a.x * b.x + a.y * b.y + a.z * b.z + a.w * b.w;
    }
    d *= inv;
    float mx = d;
    #pragma unroll
    for (int off = 8; off; off >>= 1) mx = fmaxf(mx, __shfl_xor(mx, off, 16));
    float e = expf(d - mx);
    float s = e;
    #pragma unroll
    for (int off = 8; off; off >>= 1) s += __shfl_xor(s, off, 16);
    p[(size_t)row * 16 + k] = e / s;
}

// am[b,k,c] = exp(dot(Q[k],Kk[b,c])/sqrt(H)) * bernoulli_mask; 16 rows/block
__global__ __launch_bounds__(256) void attn_scores(const float* __restrict__ Kk,
                                                   const float* __restrict__ Q,
                                                   const float* __restrict__ pbuf,
                                                   float* __restrict__ am) {
    int tid = threadIdx.x;
    int k = tid >> 4, r = tid & 15;
    int row = blockIdx.x * 16 + r;           // row = b*C + c
    int b = row >> 9, c = row & 511;
    const float4* kp = (const float4*)(Kk + (size_t)row * 512);
    const float4* qp = (const float4*)(Q + (size_t)k * 512);
    float d = 0.f;
    for (int j = 0; j < 128; ++j) {
        float4 a = kp[j], q = qp[j];
        d += a.x * q.x + a.y * q.y + a.z * q.z + a.w * q.w;
    }
    d *= 0.044194173824159216f;  // 1/sqrt(512)
    // fused jax bernoulli(key(42)): flat index j over [B,C,K]
    int j = row * 16 + k;
    const int HALF = (B_ * C_ * K_) / 2;
    unsigned x0 = (j < HALF) ? (unsigned)j : (unsigned)(j - HALF);
    unsigned x1 = x0 + (unsigned)HALF;
    threefry2x32(0u, 42u, x0, x1);
    unsigned bits = (j < HALF) ? x0 : x1;
    float u = __uint_as_float((bits >> 9) | 0x3f800000u) - 1.0f;
    float m = (u < pbuf[j]) ? 1.0f : 0.0f;
    am[((size_t)b * 16 + k) * 512 + c] = expf(d) * m;
}

// recip[b,k] = 1 / sum_c am[b,k,c]
__global__ __launch_bounds__(256) void row_recip(const float* __restrict__ am,
                                                 float* __restrict__ recip) {
    int rk = blockIdx.x, tid = threadIdx.x;
    float2 v = ((const float2*)(am + (size_t)rk * 512))[tid];
    float s = v.x + v.y, dummy = 0.f;
    block_sum2_256(s, dummy);
    if (tid == 0) recip[rk] = 1.0f / s;
}

// partial Cc: block (b, cs) sums c-range of 64; slab out [b*8+cs][k*512+h]
__global__ __launch_bounds__(256) void cc_partial(const float* __restrict__ am,
                                                  const float* __restrict__ recip,
                                                  const u16* __restrict__ V16,
                                                  float* __restrict__ Ccp) {
    int b = blockIdx.x, cs = blockIdx.y;
    int c0 = cs * 64, tid = threadIdx.x;
    __shared__ float awS[16 * 64];
    for (int idx = tid; idx < 1024; idx += 256) {
        int k = idx >> 6, cj = idx & 63;
        awS[idx] = am[((size_t)b * 16 + k) * 512 + c0 + cj] * recip[b * 16 + k];
    }
    __syncthreads();
    float acc0[16] = {}, acc1[16] = {};
    for (int cj = 0; cj < 64; ++cj) {
        const u16* vp = V16 + ((size_t)(b * 512) + c0 + cj) * 512;
        unsigned pk = ((const unsigned*)vp)[tid];     // bf16 pair h=2tid,2tid+1
        float v0 = bf2f((u16)(pk & 0xffffu));
        float v1 = bf2f((u16)(pk >> 16));
        #pragma unroll
        for (int k = 0; k < 16; ++k) {
            float a = awS[k * 64 + cj];
            acc0[k] += a * v0;
            acc1[k] += a * v1;
        }
    }
    float* out = Ccp + ((size_t)(b * 8 + cs)) * 8192;
    #pragma unroll
    for (int k = 0; k < 16; ++k) {
        float2 o; o.x = acc0[k]; o.y = acc1[k];
        ((float2*)(out + k * 512))[tid] = o;
    }
}

// ce_new[k,h] = (1/B) * sum over 256 slabs
__global__ __launch_bounds__(256) void cc_mean(const float* __restrict__ Ccp,
                                               float* __restrict__ ce) {
    int idx = blockIdx.x * 256 + threadIdx.x;  // < 8192
    float s = 0.f;
    for (int sl = 0; sl < 256; ++sl) s += Ccp[(size_t)sl * 8192 + idx];
    ce[idx] = s * (1.0f / B_);
}

// out partial: block (c, hs): partial[hs][c][b*96+p] over h-range 128,
// theta = p . ce_new fused on the fly
__global__ __launch_bounds__(256) void out_partial(const float* __restrict__ Hm,
                                                   const float* __restrict__ pbuf,
                                                   const float* __restrict__ ce,
                                                   const float* __restrict__ out_w,
                                                   float* __restrict__ Pp) {
    int c = blockIdx.x, hs = blockIdx.y, tid = threadIdx.x;
    int h0 = hs * 128;
    __shared__ float wS[32 * 96];
    __shared__ float gS[32 * 33];
    __shared__ float ceS[16 * 32];
    __shared__ float pS[32 * 16];
    for (int idx = tid; idx < 512; idx += 256) {
        int b = idx >> 4, k = idx & 15;
        pS[idx] = pbuf[((size_t)(b * 512 + c)) * 16 + k];
    }
    int b_own = tid >> 3, pb = (tid & 7) * 12;
    float acc[12] = {};
    const size_t wbase = (size_t)c * 512 * 96;
    for (int hc = 0; hc < 4; ++hc) {
        int hh0 = h0 + hc * 32;
        __syncthreads();
        for (int idx = tid; idx < 768; idx += 256)
            ((float4*)wS)[idx] = ((const float4*)(out_w + wbase + (size_t)hh0 * 96))[idx];
        for (int idx = tid; idx < 512; idx += 256) {
            int k = idx >> 5, hh = idx & 31;
            ceS[idx] = ce[k * 512 + hh0 + hh];
        }
        __syncthreads();
        {
            int b = tid >> 3, hq = (tid & 7) * 4;
            float4 hv = *(const float4*)(Hm + ((size_t)(b * 512 + c)) * 512 + hh0 + hq);
            float hvv[4] = {hv.x, hv.y, hv.z, hv.w};
            #pragma unroll
            for (int j = 0; j < 4; ++j) {
                float s = 0.f;
                #pragma unroll
                for (int k = 0; k < 16; ++k) s += pS[b * 16 + k] * ceS[k * 32 + hq + j];
                gS[b * 33 + hq + j] = hvv[j] * s;
            }
        }
        __syncthreads();
        #pragma unroll 8
        for (int hh = 0; hh < 32; ++hh) {
            float g = gS[b_own * 33 + hh];
            #pragma unroll
            for (int j = 0; j < 12; ++j) acc[j] += g * wS[hh * 96 + pb + j];
        }
    }
    float* pp = Pp + ((size_t)hs * 512 + c) * 3072 + b_own * 96 + pb;
    #pragma unroll
    for (int j = 0; j < 12; ++j) pp[j] = acc[j];
}

// final: sum 4 slabs + bias, denorm, write out[b][p][c]
__global__ __launch_bounds__(256) void out_final(const float* __restrict__ Pp,
                                                 const float* __restrict__ out_b,
                                                 const float* __restrict__ rev_w,
                                                 const float* __restrict__ rev_b,
                                                 const float* __restrict__ meanB,
                                                 const float* __restrict__ stdB,
                                                 float* __restrict__ out) {
    int c = blockIdx.x, tid = threadIdx.x;
    float inv_rw = 1.0f / (rev_w[c] + 1e-10f);
    float rb = rev_b[c];
    for (int idx = tid; idx < 3072; idx += 256) {
        int b = idx / 96, p = idx - b * 96;
        float v = out_b[(size_t)c * 96 + p];
        #pragma unroll
        for (int hs = 0; hs < 4; ++hs)
            v += Pp[((size_t)hs * 512 + c) * 3072 + idx];
        float y = (v - rb) * inv_rw * stdB[b * 512 + c] + meanB[b * 512 + c];
        out[((size_t)b * 96 + p) * 512 + c] = y;
    }
}

// ---------------------------------------------------------------- launch

extern "C" void kernel_launch(void* const* d_in, const int* in_sizes, int n_in,
                              void* d_out, int out_size, void* d_ws, size_t ws_size,
                              hipStream_t stream) {
    const float* x        = (const float*)d_in[0];
    const float* rev_w    = (const float*)d_in[1];
    const float* rev_b    = (const float*)d_in[2];
    const float* mlp_w1   = (const float*)d_in[3];
    const float* mlp_b1   = (const float*)d_in[4];
    const float* mlp_w2   = (const float*)d_in[5];
    const float* mlp_b2   = (const float*)d_in[6];
    const float* clu_emb  = (const float*)d_in[7];
    const float* wq       = (const float*)d_in[8];
    const float* bq       = (const float*)d_in[9];
    const float* wk       = (const float*)d_in[10];
    const float* bk       = (const float*)d_in[11];
    const float* wv       = (const float*)d_in[12];
    const float* bv       = (const float*)d_in[13];
    const float* ts_ln_g  = (const float*)d_in[14];
    const float* ts_ln_b  = (const float*)d_in[15];
    const float* ts_w     = (const float*)d_in[16];
    const float* ts_b     = (const float*)d_in[17];
    const float* ch_ln_g  = (const float*)d_in[18];
    const float* ch_ln_b  = (const float*)d_in[19];
    const float* ch_w1    = (const float*)d_in[20];
    const float* ch_b1    = (const float*)d_in[21];
    const float* ch_w2    = (const float*)d_in[22];
    const float* ch_b2    = (const float*)d_in[23];
    const float* out_w    = (const float*)d_in[24];
    const float* out_b    = (const float*)d_in[25];

    float* f = (float*)d_ws;
    const size_t SLOT = (size_t)(B_ * C_) * H_;   // 8388608 floats
    float* F0 = f;                 // h32 -> Hm32
    float* F1 = f + SLOT;          // Kk32 -> Ccp -> U32 -> Pp
    u16*  X16 = (u16*)(f + 2 * SLOT);            // xt -> h16 -> G16
    u16*  T16 = (u16*)(f + 2 * SLOT + SLOT / 2); // h1 -> V16 -> N16
    float* sm = f + 3 * SLOT;
    u16* Wt[7];
    for (int i = 0; i < 7; ++i) { Wt[i] = (u16*)sm; sm += 131072; }  // 512*512 bf16
    float* meanB  = sm; sm += B_ * C_;
    float* stdB   = sm; sm += B_ * C_;
    float* pbuf   = sm; sm += B_ * C_ * K_;
    float* ambuf  = sm; sm += B_ * K_ * C_;
    float* recips = sm; sm += B_ * K_;
    float* cebuf  = sm; sm += K_ * H_;
    float* cnbuf  = sm; sm += K_ * H_;
    float* Qbuf   = sm; sm += K_ * H_;
    float* Ccp = F1;   // 256*8192 floats, aliases F1 (Kk dead)
    float* Pp  = F1;   // 4*512*3072 floats, aliases F1 (U32 dead)

    dim3 ggrid(4, 128);              // N/128, M/128
    dim3 t_grid(B_, 16, 16);
    dim3 t_blk(32, 8);
    const int Mrows = B_ * C_;

    // RevIN + transpose (bf16)
    revin_stats<<<dim3(B_, 2), 256, 0, stream>>>(x, meanB, stdB);
    transpose_revin<<<t_grid, t_blk, 0, stream>>>(x, meanB, stdB, rev_w, rev_b, X16);
    // weight convert+transpose: mlp_w1, mlp_w2, wk, wv, ts_w, ch_w1, ch_w2
    WPtrs wp;
    wp.src[0] = mlp_w1; wp.src[1] = mlp_w2; wp.src[2] = wk; wp.src[3] = wv;
    wp.src[4] = ts_w;   wp.src[5] = ch_w1;  wp.src[6] = ch_w2;
    for (int i = 0; i < 7; ++i) wp.dst[i] = Wt[i];
    convert_w<<<dim3(16, 16, 7), t_blk, 0, stream>>>(wp);
    // Q (fp32 tiny)
    gemm_f32<<<dim3(8, 1), 256, 0, stream>>>(clu_emb, wq, bq, Qbuf, K_, H_, H_);
    // channel MLP (bf16 MFMA)
    gemm_bf16<1><<<ggrid, 256, 0, stream>>>(X16, Wt[0], mlp_b1, nullptr, T16,
                                            Mrows, H_, L_);
    gemm_bf16<5><<<ggrid, 256, 0, stream>>>(T16, Wt[1], mlp_b2, F0, X16,
                                            Mrows, H_, H_);
    // routing
    normalize_rows16<<<K_, 256, 0, stream>>>(clu_emb, cnbuf);
    routing_kernel<<<Mrows / 16, 256, 0, stream>>>(F0, cnbuf, pbuf);
    // K, V projections
    gemm_bf16<0><<<ggrid, 256, 0, stream>>>(X16, Wt[2], bk, F1, nullptr,
                                            Mrows, H_, H_);
    gemm_bf16<6><<<ggrid, 256, 0, stream>>>(X16, Wt[3], bv, nullptr, T16,
                                            Mrows, H_, H_);
    // masked attention -> ce_new
    attn_scores<<<Mrows / 16, 256, 0, stream>>>(F1, Qbuf, pbuf, ambuf);
    row_recip<<<B_ * K_, 256, 0, stream>>>(ambuf, recips);
    cc_partial<<<dim3(B_, 8), 256, 0, stream>>>(ambuf, recips, T16, Ccp);
    cc_mean<<<(K_ * H_) / 256, 256, 0, stream>>>(Ccp, cebuf);
    // mixer in [B,H,C] layout
    transpose_b<<<t_grid, t_blk, 0, stream>>>(F0, F1);        // h32 -> U32
    for (int it = 0; it < NB_; ++it) {
        ln_rows<<<Mrows, 256, 0, stream>>>(F1, T16, ts_ln_g, ts_ln_b);
        gemm_bf16<3><<<ggrid, 256, 0, stream>>>(T16, Wt[4], ts_b, F1, nullptr,
                                                Mrows, C_, C_);
        ln_rows<<<Mrows, 256, 0, stream>>>(F1, T16, ch_ln_g, ch_ln_b);
        gemm_bf16<2><<<ggrid, 256, 0, stream>>>(T16, Wt[5], ch_b1, nullptr, X16,
                                                Mrows, H_, C_);
        gemm_bf16<4><<<ggrid, 256, 0, stream>>>(X16, Wt[6], ch_b2, F1, nullptr,
                                                Mrows, C_, H_);
    }
    transpose_b<<<t_grid, t_blk, 0, stream>>>(F1, F0);        // U32 -> Hm32
    // expert projection + denorm
    out_partial<<<dim3(C_, 4), 256, 0, stream>>>(F0, pbuf, cebuf, out_w, Pp);
    out_final<<<C_, 256, 0, stream>>>(Pp, out_b, rev_w, rev_b, meanB, stdB,
                                      (float*)d_out);
}

// Round 3
// 1169.924 us; speedup vs baseline: 2.3692x; 1.0012x over previous
//
#include <hip/hip_runtime.h>
#include <math.h>

#define B_  32
#define L_  512
#define C_  512
#define H_  512
#define K_  16
#define P_  96
#define NB_ 4

typedef unsigned short u16;
typedef __attribute__((ext_vector_type(8))) __bf16 bf16x8;
typedef __attribute__((ext_vector_type(4))) float f32x4;

// ---------------------------------------------------------------- helpers

__device__ __forceinline__ float gelu_f(float x) {
    return 0.5f * x * (1.0f + erff(x * 0.70710678118654752440f));
}

__device__ __forceinline__ u16 f2bf(float f) {
    union { float f; unsigned u; } v; v.f = f;
    unsigned r = v.u + 0x7fffu + ((v.u >> 16) & 1u);   // RNE
    return (u16)(r >> 16);
}
__device__ __forceinline__ float bf2f(u16 h) {
    union { unsigned u; float f; } v; v.u = ((unsigned)h) << 16;
    return v.f;
}

// block(256) dual sum reduce; call at most once per kernel
__device__ __forceinline__ void block_sum2_256(float& a, float& b) {
    __shared__ float la[4], lb[4];
    #pragma unroll
    for (int off = 32; off; off >>= 1) {
        a += __shfl_down(a, off);
        b += __shfl_down(b, off);
    }
    int wid = threadIdx.x >> 6;
    if ((threadIdx.x & 63) == 0) { la[wid] = a; lb[wid] = b; }
    __syncthreads();
    a = la[0] + la[1] + la[2] + la[3];
    b = lb[0] + lb[1] + lb[2] + lb[3];
}

// JAX threefry2x32, key = (k0,k1)
__device__ __forceinline__ void threefry2x32(unsigned k0, unsigned k1,
                                             unsigned& x0, unsigned& x1) {
    const unsigned ks0 = k0, ks1 = k1, ks2 = k0 ^ k1 ^ 0x1BD11BDAu;
    x0 += ks0; x1 += ks1;
#define TF_ROT(v, r) (((v) << (r)) | ((v) >> (32 - (r))))
#define TF_R(r) { x0 += x1; x1 = TF_ROT(x1, r); x1 ^= x0; }
    TF_R(13) TF_R(15) TF_R(26) TF_R(6)   x0 += ks1; x1 += ks2 + 1u;
    TF_R(17) TF_R(29) TF_R(16) TF_R(24)  x0 += ks2; x1 += ks0 + 2u;
    TF_R(13) TF_R(15) TF_R(26) TF_R(6)   x0 += ks0; x1 += ks1 + 3u;
    TF_R(17) TF_R(29) TF_R(16) TF_R(24)  x0 += ks1; x1 += ks2 + 4u;
    TF_R(13) TF_R(15) TF_R(26) TF_R(6)   x0 += ks2; x1 += ks0 + 5u;
#undef TF_R
#undef TF_ROT
}

#define GLL16(g, l) __builtin_amdgcn_global_load_lds( \
    (const __attribute__((address_space(1))) void*)(g), \
    (__attribute__((address_space(3))) void*)(l), 16, 0, 0)

// ---------------------------------------------------------------- kernels

// per-(b,c) mean/std over L (x is [B,L,C])
__global__ __launch_bounds__(256) void revin_stats(const float* __restrict__ x,
                                                   float* __restrict__ meanB,
                                                   float* __restrict__ stdB) {
    int b = blockIdx.x;
    int c = blockIdx.y * 256 + threadIdx.x;
    const float* xp = x + (size_t)b * L_ * C_ + c;
    float s = 0.f, ss = 0.f;
    for (int l = 0; l < L_; ++l) {
        float v = xp[(size_t)l * C_];
        s += v; ss += v * v;
    }
    float m = s * (1.0f / L_);
    float var = ss * (1.0f / L_) - m * m;
    meanB[b * C_ + c] = m;
    stdB[b * C_ + c]  = sqrtf(var + 1e-5f);
}

// x [B,L,C] -> xt bf16 [B,C,L] with RevIN applied
__global__ __launch_bounds__(256) void transpose_revin(const float* __restrict__ x,
                                                       const float* __restrict__ meanB,
                                                       const float* __restrict__ stdB,
                                                       const float* __restrict__ rw,
                                                       const float* __restrict__ rb,
                                                       u16* __restrict__ xt) {
    __shared__ float tile[32][33];
    int b = blockIdx.x, l0 = blockIdx.y * 32, c0 = blockIdx.z * 32;
    int tx = threadIdx.x, ty = threadIdx.y;
    for (int i = ty; i < 32; i += 8) {
        int l = l0 + i, c = c0 + tx;
        float v = x[((size_t)b * L_ + l) * C_ + c];
        v = (v - meanB[b * C_ + c]) / stdB[b * C_ + c] * rw[c] + rb[c];
        tile[i][tx] = v;
    }
    __syncthreads();
    for (int i = ty; i < 32; i += 8) {
        int c = c0 + i, l = l0 + tx;
        xt[((size_t)b * C_ + c) * L_ + l] = f2bf(tile[tx][i]);
    }
}

// plain per-batch 512x512 fp32 transpose
__global__ __launch_bounds__(256) void transpose_b(const float* __restrict__ in,
                                                   float* __restrict__ out) {
    __shared__ float tile[32][33];
    int b = blockIdx.x, r0 = blockIdx.y * 32, c0 = blockIdx.z * 32;
    int tx = threadIdx.x, ty = threadIdx.y;
    for (int i = ty; i < 32; i += 8)
        tile[i][tx] = in[((size_t)b * 512 + r0 + i) * 512 + c0 + tx];
    __syncthreads();
    for (int i = ty; i < 32; i += 8)
        out[((size_t)b * 512 + c0 + i) * 512 + r0 + tx] = tile[tx][i];
}

// 7 weight matrices [512][512] f32 -> transposed bf16 [512][512]
struct WPtrs { const float* src[7]; u16* dst[7]; };
__global__ __launch_bounds__(256) void convert_w(WPtrs wp) {
    __shared__ float tile[32][33];
    int wi = blockIdx.z;
    const float* src = wp.src[wi];
    u16* dst = wp.dst[wi];
    int r0 = blockIdx.y * 32, c0 = blockIdx.x * 32;
    int tx = threadIdx.x, ty = threadIdx.y;
    for (int i = ty; i < 32; i += 8)
        tile[i][tx] = src[(size_t)(r0 + i) * 512 + c0 + tx];
    __syncthreads();
    for (int i = ty; i < 32; i += 8)
        dst[(size_t)(c0 + i) * 512 + r0 + tx] = f2bf(tile[tx][i]);
}

// bf16 MFMA GEMM (m97 structure): 128x128 tile, BK=32, 256 thr (4 waves 2x2)
// EPI: 0 store f32 | 1 relu->bf16 | 5 store f32 AND bf16 | 6 store bf16
template <int EPI>
__global__ __launch_bounds__(256) void gemm_bf16(const u16* __restrict__ A,
                                                 const u16* __restrict__ Bt,
                                                 const float* __restrict__ bias,
                                                 float* __restrict__ C32,
                                                 u16* __restrict__ C16,
                                                 int M, int N, int K) {
    __shared__ u16 As[128 * 32];
    __shared__ u16 Bs[128 * 32];
    int tid = threadIdx.x;
    int m0 = blockIdx.y * 128, n0 = blockIdx.x * 128;
    int lane = tid & 63, wave = tid >> 6;
    int wm = wave >> 1, wn = wave & 1;
    int col = lane & 15, quad = lane >> 4;
    int koff = quad * 8;

    int qa0 = tid, qa1 = tid + 256;
    const u16* Ag0 = A + (size_t)(m0 + (qa0 >> 2)) * K + (qa0 & 3) * 8;
    const u16* Ag1 = A + (size_t)(m0 + (qa1 >> 2)) * K + (qa1 & 3) * 8;
    const u16* Bg0 = Bt + (size_t)(n0 + (qa0 >> 2)) * K + (qa0 & 3) * 8;
    const u16* Bg1 = Bt + (size_t)(n0 + (qa1 >> 2)) * K + (qa1 & 3) * 8;
    u16* Al0 = &As[qa0 * 8];
    u16* Al1 = &As[qa1 * 8];
    u16* Bl0 = &Bs[qa0 * 8];
    u16* Bl1 = &Bs[qa1 * 8];

    f32x4 acc[4][4];
    #pragma unroll
    for (int i = 0; i < 4; ++i)
        #pragma unroll
        for (int j = 0; j < 4; ++j)
            acc[i][j] = (f32x4){0.f, 0.f, 0.f, 0.f};

    for (int k0 = 0; k0 < K; k0 += 32) {
        GLL16(Ag0 + k0, Al0);
        GLL16(Ag1 + k0, Al1);
        GLL16(Bg0 + k0, Bl0);
        GLL16(Bg1 + k0, Bl1);
        __syncthreads();
        bf16x8 af[4], bfr[4];
        #pragma unroll
        for (int mt = 0; mt < 4; ++mt)
            af[mt] = *(const bf16x8*)&As[(wm * 64 + mt * 16 + col) * 32 + koff];
        #pragma unroll
        for (int nt = 0; nt < 4; ++nt)
            bfr[nt] = *(const bf16x8*)&Bs[(wn * 64 + nt * 16 + col) * 32 + koff];
        #pragma unroll
        for (int mt = 0; mt < 4; ++mt)
            #pragma unroll
            for (int nt = 0; nt < 4; ++nt)
                acc[mt][nt] = __builtin_amdgcn_mfma_f32_16x16x32_bf16(
                    af[mt], bfr[nt], acc[mt][nt], 0, 0, 0);
        __syncthreads();
    }

    float bb[4];
    #pragma unroll
    for (int nt = 0; nt < 4; ++nt) bb[nt] = bias[n0 + wn * 64 + nt * 16 + col];
    #pragma unroll
    for (int mt = 0; mt < 4; ++mt) {
        int mbase = m0 + wm * 64 + mt * 16 + quad * 4;
        #pragma unroll
        for (int r = 0; r < 4; ++r) {
            size_t rowoff = (size_t)(mbase + r) * N;
            #pragma unroll
            for (int nt = 0; nt < 4; ++nt) {
                int gn = n0 + wn * 64 + nt * 16 + col;
                float t = acc[mt][nt][r] + bb[nt];
                if (EPI == 1) t = fmaxf(t, 0.f);
                if (EPI == 0) {
                    C32[rowoff + gn] = t;
                } else if (EPI == 1 || EPI == 6) {
                    C16[rowoff + gn] = f2bf(t);
                } else if (EPI == 5) {
                    C32[rowoff + gn] = t;
                    C16[rowoff + gn] = f2bf(t);
                }
            }
        }
    }
}

// fp32 tiled GEMM (only for tiny Q = clu_emb @ wq + bq, M=16)
__global__ __launch_bounds__(256) void gemm_f32(const float* __restrict__ A,
                                                const float* __restrict__ Bm,
                                                const float* __restrict__ bias,
                                                float* __restrict__ Cm,
                                                int M, int N, int K) {
    __shared__ float As[16][64];
    __shared__ float Bs[16][64];
    int tid = threadIdx.x;
    int tx = tid & 15, ty = tid >> 4;
    int m0 = blockIdx.y * 64, n0 = blockIdx.x * 64;
    float acc[4][4] = {};
    for (int k0 = 0; k0 < K; k0 += 16) {
        {
            int r = tid >> 2, cc = (tid & 3) * 4, gm = m0 + r;
            float4 v = make_float4(0.f, 0.f, 0.f, 0.f);
            if (gm < M) v = *(const float4*)(A + (size_t)gm * K + k0 + cc);
            As[cc + 0][r] = v.x; As[cc + 1][r] = v.y;
            As[cc + 2][r] = v.z; As[cc + 3][r] = v.w;
        }
        {
            int r = tid >> 4, cc = (tid & 15) * 4;
            *(float4*)&Bs[r][cc] = *(const float4*)(Bm + (size_t)(k0 + r) * N + n0 + cc);
        }
        __syncthreads();
        #pragma unroll
        for (int kk = 0; kk < 16; ++kk) {
            float4 a4 = *(const float4*)&As[kk][ty * 4];
            float4 b4 = *(const float4*)&Bs[kk][tx * 4];
            float av[4] = {a4.x, a4.y, a4.z, a4.w};
            float bv[4] = {b4.x, b4.y, b4.z, b4.w};
            #pragma unroll
            for (int i = 0; i < 4; ++i)
                #pragma unroll
                for (int j = 0; j < 4; ++j)
                    acc[i][j] += av[i] * bv[j];
        }
        __syncthreads();
    }
    int gn = n0 + tx * 4;
    float4 b4 = *(const float4*)(bias + gn);
    float bb[4] = {b4.x, b4.y, b4.z, b4.w};
    #pragma unroll
    for (int i = 0; i < 4; ++i) {
        int gm = m0 + ty * 4 + i;
        if (gm >= M) break;
        float* cp = Cm + (size_t)gm * N + gn;
        *(float4*)cp = make_float4(acc[i][0] + bb[0], acc[i][1] + bb[1],
                                   acc[i][2] + bb[2], acc[i][3] + bb[3]);
    }
}

// normalize 16 rows of 512 (cluster embeds -> cn)
__global__ __launch_bounds__(256) void normalize_rows16(const float* __restrict__ ce,
                                                        float* __restrict__ cn) {
    int k = blockIdx.x, tid = threadIdx.x;
    float2 v = ((const float2*)(ce + (size_t)k * 512))[tid];
    float ss = v.x * v.x + v.y * v.y, dummy = 0.f;
    block_sum2_256(ss, dummy);
    float inv = 1.0f / fmaxf(sqrtf(ss), 1e-12f);
    float2 o; o.x = v.x * inv; o.y = v.y * inv;
    ((float2*)(cn + (size_t)k * 512))[tid] = o;
}

// p[b,c,k] = softmax_k( cos(h[b,c,:], cn[k,:]) ); block handles 16 rows
__global__ __launch_bounds__(256) void routing_kernel(const float* __restrict__ h,
                                                      const float* __restrict__ cn,
                                                      float* __restrict__ p) {
    int tid = threadIdx.x;
    int r = tid >> 4, k = tid & 15;
    int row = blockIdx.x * 16 + r;
    const float4* hp = (const float4*)(h + (size_t)row * 512);
    const float4* ck = (const float4*)(cn + (size_t)k * 512);
    float ss = 0.f;
    #pragma unroll
    for (int j = k * 8; j < k * 8 + 8; ++j) {
        float4 v = hp[j];
        ss += v.x * v.x + v.y * v.y + v.z * v.z + v.w * v.w;
    }
    #pragma unroll
    for (int off = 8; off; off >>= 1) ss += __shfl_xor(ss, off, 16);
    float inv = 1.0f / fmaxf(sqrtf(ss), 1e-12f);
    float d = 0.f;
    for (int j = 0; j < 128; ++j) {
        float4 a = hp[j], b = ck[j];
        d += a.x * b.x + a.y * b.y + a.z * b.z + a.w * b.w;
    }
    d *= inv;
    float mx = d;
    #pragma unroll
    for (int off = 8; off; off >>= 1) mx = fmaxf(mx, __shfl_xor(mx, off, 16));
    float e = expf(d - mx);
    float s = e;
    #pragma unroll
    for (int off = 8; off; off >>= 1) s += __shfl_xor(s, off, 16);
    p[(size_t)row * 16 + k] = e / s;
}

// am[b,k,c] = exp(dot(Q[k],Kk[b,c])/sqrt(H)) * bernoulli_mask; 16 rows/block
__global__ __launch_bounds__(256) void attn_scores(const float* __restrict__ Kk,
                                                   const float* __restrict__ Q,
                                                   const float* __restrict__ pbuf,
                                                   float* __restrict__ am) {
    int tid = threadIdx.x;
    int k = tid >> 4, r = tid & 15;
    int row = blockIdx.x * 16 + r;           // row = b*C + c
    int b = row >> 9, c = row & 511;
    const float4* kp = (const float4*)(Kk + (size_t)row * 512);
    const float4* qp = (const float4*)(Q + (size_t)k * 512);
    float d = 0.f;
    for (int j = 0; j < 128; ++j) {
        float4 a = kp[j], q = qp[j];
        d += a.x * q.x + a.y * q.y + a.z * q.z + a.w * q.w;
    }
    d *= 0.044194173824159216f;  // 1/sqrt(512)
    int j = row * 16 + k;
    const int HALF = (B_ * C_ * K_) / 2;
    unsigned x0 = (j < HALF) ? (unsigned)j : (unsigned)(j - HALF);
    unsigned x1 = x0 + (unsigned)HALF;
    threefry2x32(0u, 42u, x0, x1);
    unsigned bits = (j < HALF) ? x0 : x1;
    float u = __uint_as_float((bits >> 9) | 0x3f800000u) - 1.0f;
    float m = (u < pbuf[j]) ? 1.0f : 0.0f;
    am[((size_t)b * 16 + k) * 512 + c] = expf(d) * m;
}

// recip[b,k] = 1 / sum_c am[b,k,c]
__global__ __launch_bounds__(256) void row_recip(const float* __restrict__ am,
                                                 float* __restrict__ recip) {
    int rk = blockIdx.x, tid = threadIdx.x;
    float2 v = ((const float2*)(am + (size_t)rk * 512))[tid];
    float s = v.x + v.y, dummy = 0.f;
    block_sum2_256(s, dummy);
    if (tid == 0) recip[rk] = 1.0f / s;
}

// partial Cc: block (b, cs) sums c-range of 64; slab out [b*8+cs][k*512+h]
__global__ __launch_bounds__(256) void cc_partial(const float* __restrict__ am,
                                                  const float* __restrict__ recip,
                                                  const u16* __restrict__ V16,
                                                  float* __restrict__ Ccp) {
    int b = blockIdx.x, cs = blockIdx.y;
    int c0 = cs * 64, tid = threadIdx.x;
    __shared__ float awS[16 * 64];
    for (int idx = tid; idx < 1024; idx += 256) {
        int k = idx >> 6, cj = idx & 63;
        awS[idx] = am[((size_t)b * 16 + k) * 512 + c0 + cj] * recip[b * 16 + k];
    }
    __syncthreads();
    float acc0[16] = {}, acc1[16] = {};
    for (int cj = 0; cj < 64; ++cj) {
        const u16* vp = V16 + ((size_t)(b * 512) + c0 + cj) * 512;
        unsigned pk = ((const unsigned*)vp)[tid];
        float v0 = bf2f((u16)(pk & 0xffffu));
        float v1 = bf2f((u16)(pk >> 16));
        #pragma unroll
        for (int k = 0; k < 16; ++k) {
            float a = awS[k * 64 + cj];
            acc0[k] += a * v0;
            acc1[k] += a * v1;
        }
    }
    float* out = Ccp + ((size_t)(b * 8 + cs)) * 8192;
    #pragma unroll
    for (int k = 0; k < 16; ++k) {
        float2 o; o.x = acc0[k]; o.y = acc1[k];
        ((float2*)(out + k * 512))[tid] = o;
    }
}

// ce_new[k,h] = (1/B) * sum over 256 slabs
__global__ __launch_bounds__(256) void cc_mean(const float* __restrict__ Ccp,
                                               float* __restrict__ ce) {
    int idx = blockIdx.x * 256 + threadIdx.x;  // < 8192
    float s = 0.f;
    for (int sl = 0; sl < 256; ++sl) s += Ccp[(size_t)sl * 8192 + idx];
    ce[idx] = s * (1.0f / B_);
}

// ---------------------------------------------------------------- fused mixer
// One block = 32 rows of z [16384][512]; 4 iterations entirely in-register.
// z row-major fp32 global in/out. Weights bf16 pre-transposed [n][k].
__global__ __launch_bounds__(256) void mixer_fused(
    float* __restrict__ z,
    const u16* __restrict__ tsw, const u16* __restrict__ chw1,
    const u16* __restrict__ chw2,
    const float* __restrict__ tslng, const float* __restrict__ tslnb,
    const float* __restrict__ tsb,
    const float* __restrict__ chlng, const float* __restrict__ chlnb,
    const float* __restrict__ chb1, const float* __restrict__ chb2) {
    __shared__ u16 A16[32 * 520];
    __shared__ float statS[32 * 2];
    __shared__ float partS[4 * 32 * 2];
    __shared__ float vecS[7 * 512];

    int tid = threadIdx.x, lane = tid & 63, wave = tid >> 6;
    int col = lane & 15, quad = lane >> 4;
    int m0 = blockIdx.x * 32;

    // stage the 7 per-column vectors
    {
        const float* vsrc[7] = {tslng, tslnb, tsb, chlng, chlnb, chb1, chb2};
        for (int i = tid; i < 7 * 512; i += 256) vecS[i] = vsrc[i >> 9][i & 511];
    }

    // load z rows into registers, C-layout: zr[mt*8+nt][r] =
    //   z[m0 + mt*16 + quad*4 + r][wave*128 + nt*16 + col]
    f32x4 zr[16];
    float* zbase = z + (size_t)m0 * 512;
    #pragma unroll
    for (int mt = 0; mt < 2; ++mt)
        #pragma unroll
        for (int nt = 0; nt < 8; ++nt)
            #pragma unroll
            for (int r = 0; r < 4; ++r)
                zr[mt * 8 + nt][r] =
                    zbase[(size_t)(mt * 16 + quad * 4 + r) * 512 +
                          wave * 128 + nt * 16 + col];

    auto stats = [&]() {
        #pragma unroll
        for (int mt = 0; mt < 2; ++mt)
            #pragma unroll
            for (int r = 0; r < 4; ++r) {
                float s = 0.f, ss = 0.f;
                #pragma unroll
                for (int nt = 0; nt < 8; ++nt) {
                    float v = zr[mt * 8 + nt][r];
                    s += v; ss += v * v;
                }
                #pragma unroll
                for (int o = 8; o; o >>= 1) {
                    s += __shfl_xor(s, o, 16);
                    ss += __shfl_xor(ss, o, 16);
                }
                if (col == 0) {
                    int m = mt * 16 + quad * 4 + r;
                    partS[(wave * 32 + m) * 2 + 0] = s;
                    partS[(wave * 32 + m) * 2 + 1] = ss;
                }
            }
        __syncthreads();
        if (tid < 32) {
            float s = 0.f, ss = 0.f;
            #pragma unroll
            for (int w = 0; w < 4; ++w) {
                s += partS[(w * 32 + tid) * 2];
                ss += partS[(w * 32 + tid) * 2 + 1];
            }
            float mean = s * (1.0f / 512.0f);
            float var = ss * (1.0f / 512.0f) - mean * mean;
            statS[tid * 2] = mean;
            statS[tid * 2 + 1] = rsqrtf(var + 1e-5f);
        }
        __syncthreads();
    };

    auto writeNorm = [&](int gi, int bi) {
        float mn[8], rs[8];
        #pragma unroll
        for (int mt = 0; mt < 2; ++mt)
            #pragma unroll
            for (int r = 0; r < 4; ++r) {
                int m = mt * 16 + quad * 4 + r;
                mn[mt * 4 + r] = statS[m * 2];
                rs[mt * 4 + r] = statS[m * 2 + 1];
            }
        #pragma unroll
        for (int nt = 0; nt < 8; ++nt) {
            int n = wave * 128 + nt * 16 + col;
            float g = vecS[gi * 512 + n], bb = vecS[bi * 512 + n];
            #pragma unroll
            for (int mt = 0; mt < 2; ++mt)
                #pragma unroll
                for (int r = 0; r < 4; ++r) {
                    int m = mt * 16 + quad * 4 + r;
                    float v = (zr[mt * 8 + nt][r] - mn[mt * 4 + r]) *
                              rs[mt * 4 + r] * g + bb;
                    A16[m * 520 + n] = f2bf(v);
                }
        }
        __syncthreads();
    };

    f32x4 acc[16];
    auto gemm = [&](const u16* __restrict__ W) {
        #pragma unroll
        for (int i = 0; i < 16; ++i) acc[i] = (f32x4){0.f, 0.f, 0.f, 0.f};
        #pragma unroll 4
        for (int kc = 0; kc < 16; ++kc) {
            bf16x8 a0 = *(const bf16x8*)&A16[col * 520 + kc * 32 + quad * 8];
            bf16x8 a1 = *(const bf16x8*)&A16[(16 + col) * 520 + kc * 32 + quad * 8];
            #pragma unroll
            for (int nt = 0; nt < 8; ++nt) {
                bf16x8 bf = *(const bf16x8*)
                    &W[(size_t)(wave * 128 + nt * 16 + col) * 512 + kc * 32 + quad * 8];
                acc[nt] = __builtin_amdgcn_mfma_f32_16x16x32_bf16(a0, bf, acc[nt], 0, 0, 0);
                acc[8 + nt] = __builtin_amdgcn_mfma_f32_16x16x32_bf16(a1, bf, acc[8 + nt], 0, 0, 0);
            }
        }
    };

    for (int it = 0; it < NB_; ++it) {
        // z += gelu(LN_ts(z) @ ts_w + ts_b)
        stats();
        writeNorm(0, 1);
        gemm(tsw);
        #pragma unroll
        for (int nt = 0; nt < 8; ++nt) {
            float bb = vecS[2 * 512 + wave * 128 + nt * 16 + col];
            #pragma unroll
            for (int mt = 0; mt < 2; ++mt)
                #pragma unroll
                for (int r = 0; r < 4; ++r)
                    zr[mt * 8 + nt][r] += gelu_f(acc[mt * 8 + nt][r] + bb);
        }
        // z += gelu(LN_ch(z) @ ch_w1 + ch_b1) @ ch_w2 + ch_b2
        stats();
        writeNorm(3, 4);
        gemm(chw1);
        __syncthreads();   // all waves done reading A16
        #pragma unroll
        for (int nt = 0; nt < 8; ++nt) {
            int n = wave * 128 + nt * 16 + col;
            float bb = vecS[5 * 512 + n];
            #pragma unroll
            for (int mt = 0; mt < 2; ++mt)
                #pragma unroll
                for (int r = 0; r < 4; ++r) {
                    int m = mt * 16 + quad * 4 + r;
                    A16[m * 520 + n] = f2bf(gelu_f(acc[mt * 8 + nt][r] + bb));
                }
        }
        __syncthreads();
        gemm(chw2);
        #pragma unroll
        for (int nt = 0; nt < 8; ++nt) {
            float bb = vecS[6 * 512 + wave * 128 + nt * 16 + col];
            #pragma unroll
            for (int mt = 0; mt < 2; ++mt)
                #pragma unroll
                for (int r = 0; r < 4; ++r)
                    zr[mt * 8 + nt][r] += acc[mt * 8 + nt][r] + bb;
        }
    }

    // store z
    #pragma unroll
    for (int mt = 0; mt < 2; ++mt)
        #pragma unroll
        for (int nt = 0; nt < 8; ++nt)
            #pragma unroll
            for (int r = 0; r < 4; ++r)
                zbase[(size_t)(mt * 16 + quad * 4 + r) * 512 +
                      wave * 128 + nt * 16 + col] = zr[mt * 8 + nt][r];
}

// ---------------------------------------------------------------- out proj
// block = one channel c: D[b=32][p=96] = (Hm*theta)[32,512] @ out_w[c][512,96]
// theta fused from pbuf/ce; K-split over 4 waves; bias+denorm epilogue.
__global__ __launch_bounds__(256) void outproj_mfma(
    const float* __restrict__ Hm, const float* __restrict__ pbuf,
    const float* __restrict__ ce, const float* __restrict__ out_w,
    const float* __restrict__ out_b, const float* __restrict__ rev_w,
    const float* __restrict__ rev_b, const float* __restrict__ meanB,
    const float* __restrict__ stdB, float* __restrict__ out) {
    __shared__ float pS[32 * 16];
    __shared__ u16 A16[32 * 520];
    __shared__ u16 Bs[4][96 * 40];
    __shared__ float redS[4][32 * 96];

    int c = blockIdx.x, tid = threadIdx.x;
    int lane = tid & 63, wave = tid >> 6;
    int col = lane & 15, quad = lane >> 4;

    for (int idx = tid; idx < 512; idx += 256) {
        int b = idx >> 4, k = idx & 15;
        pS[idx] = pbuf[((size_t)(b * 512 + c)) * 16 + k];
    }
    __syncthreads();

    // Phase A: A16[b][h] = bf16(Hm[b][c][h] * theta[b][h]),
    // theta = sum_k p[b][k]*ce[k][h]; wave owns 8 b's, lane owns 8 h's.
    {
        int h0 = lane * 8;
        f32x4 th[8][2];
        #pragma unroll
        for (int b = 0; b < 8; ++b) {
            th[b][0] = (f32x4){0.f, 0.f, 0.f, 0.f};
            th[b][1] = (f32x4){0.f, 0.f, 0.f, 0.f};
        }
        for (int k = 0; k < 16; ++k) {
            f32x4 ce0 = *(const f32x4*)&ce[k * 512 + h0];
            f32x4 ce1 = *(const f32x4*)&ce[k * 512 + h0 + 4];
            #pragma unroll
            for (int b = 0; b < 8; ++b) {
                float pk = pS[(wave * 8 + b) * 16 + k];
                th[b][0] += ce0 * pk;
                th[b][1] += ce1 * pk;
            }
        }
        #pragma unroll
        for (int b = 0; b < 8; ++b) {
            int bb = wave * 8 + b;
            const f32x4* hp = (const f32x4*)&Hm[((size_t)(bb * 512 + c)) * 512 + h0];
            f32x4 g0 = hp[0] * th[b][0];
            f32x4 g1 = hp[1] * th[b][1];
            ushort4 o0, o1;
            o0.x = f2bf(g0[0]); o0.y = f2bf(g0[1]); o0.z = f2bf(g0[2]); o0.w = f2bf(g0[3]);
            o1.x = f2bf(g1[0]); o1.y = f2bf(g1[1]); o1.z = f2bf(g1[2]); o1.w = f2bf(g1[3]);
            *(ushort4*)&A16[bb * 520 + h0] = o0;
            *(ushort4*)&A16[bb * 520 + h0 + 4] = o1;
        }
    }
    __syncthreads();

    // Phase B: wave handles kchunks wave*4 .. wave*4+3
    f32x4 pacc[12];
    #pragma unroll
    for (int i = 0; i < 12; ++i) pacc[i] = (f32x4){0.f, 0.f, 0.f, 0.f};
    const size_t wbase = (size_t)c * 512 * 96;
    for (int i = 0; i < 4; ++i) {
        int kc = wave * 4 + i;
        // stage W chunk [32 k][96 p] -> Bs[wave][p][kk] bf16 (transposed)
        {
            const float4* wsrc = (const float4*)(out_w + wbase + (size_t)kc * 32 * 96);
            #pragma unroll
            for (int t = 0; t < 12; ++t) {
                int flat4 = lane + t * 64;         // < 768
                float4 v = wsrc[flat4];
                int kk = flat4 / 24, p4 = (flat4 % 24) * 4;
                Bs[wave][(p4 + 0) * 40 + kk] = f2bf(v.x);
                Bs[wave][(p4 + 1) * 40 + kk] = f2bf(v.y);
                Bs[wave][(p4 + 2) * 40 + kk] = f2bf(v.z);
                Bs[wave][(p4 + 3) * 40 + kk] = f2bf(v.w);
            }
        }
        __syncthreads();
        #pragma unroll
        for (int mt = 0; mt < 2; ++mt) {
            bf16x8 a = *(const bf16x8*)&A16[(mt * 16 + col) * 520 + kc * 32 + quad * 8];
            #pragma unroll
            for (int nt = 0; nt < 6; ++nt) {
                bf16x8 bf = *(const bf16x8*)&Bs[wave][(nt * 16 + col) * 40 + quad * 8];
                pacc[mt * 6 + nt] = __builtin_amdgcn_mfma_f32_16x16x32_bf16(
                    a, bf, pacc[mt * 6 + nt], 0, 0, 0);
            }
        }
        __syncthreads();
    }
    // write partials
    #pragma unroll
    for (int mt = 0; mt < 2; ++mt)
        #pragma unroll
        for (int nt = 0; nt < 6; ++nt)
            #pragma unroll
            for (int r = 0; r < 4; ++r) {
                int b = mt * 16 + quad * 4 + r;
                int p = nt * 16 + col;
                redS[wave][b * 96 + p] = pacc[mt * 6 + nt][r];
            }
    __syncthreads();

    // Phase C: reduce + bias + denorm + store out[b][p][c]
    float inv_rw = 1.0f / (rev_w[c] + 1e-10f);
    float rb = rev_b[c];
    for (int e = tid; e < 3072; e += 256) {
        float v = redS[0][e] + redS[1][e] + redS[2][e] + redS[3][e];
        int b = e / 96, p = e - b * 96;
        v += out_b[(size_t)c * 96 + p];
        float y = (v - rb) * inv_rw * stdB[b * 512 + c] + meanB[b * 512 + c];
        out[((size_t)b * 96 + p) * 512 + c] = y;
    }
}

// ---------------------------------------------------------------- launch

extern "C" void kernel_launch(void* const* d_in, const int* in_sizes, int n_in,
                              void* d_out, int out_size, void* d_ws, size_t ws_size,
                              hipStream_t stream) {
    const float* x        = (const float*)d_in[0];
    const float* rev_w    = (const float*)d_in[1];
    const float* rev_b    = (const float*)d_in[2];
    const float* mlp_w1   = (const float*)d_in[3];
    const float* mlp_b1   = (const float*)d_in[4];
    const float* mlp_w2   = (const float*)d_in[5];
    const float* mlp_b2   = (const float*)d_in[6];
    const float* clu_emb  = (const float*)d_in[7];
    const float* wq       = (const float*)d_in[8];
    const float* bq       = (const float*)d_in[9];
    const float* wk       = (const float*)d_in[10];
    const float* bk       = (const float*)d_in[11];
    const float* wv       = (const float*)d_in[12];
    const float* bv       = (const float*)d_in[13];
    const float* ts_ln_g  = (const float*)d_in[14];
    const float* ts_ln_b  = (const float*)d_in[15];
    const float* ts_w     = (const float*)d_in[16];
    const float* ts_b     = (const float*)d_in[17];
    const float* ch_ln_g  = (const float*)d_in[18];
    const float* ch_ln_b  = (const float*)d_in[19];
    const float* ch_w1    = (const float*)d_in[20];
    const float* ch_b1    = (const float*)d_in[21];
    const float* ch_w2    = (const float*)d_in[22];
    const float* ch_b2    = (const float*)d_in[23];
    const float* out_w    = (const float*)d_in[24];
    const float* out_b    = (const float*)d_in[25];

    float* f = (float*)d_ws;
    const size_t SLOT = (size_t)(B_ * C_) * H_;   // 8388608 floats
    float* F0 = f;                                // h32 -> Hm32
    float* F1 = f + SLOT;                         // Kk32 -> Ccp -> z
    u16*  X16 = (u16*)(f + 2 * SLOT);             // xt -> h16
    u16*  T16 = (u16*)(f + 2 * SLOT + SLOT / 2);  // t -> V16
    float* sm = f + 3 * SLOT;
    u16* Wt[7];
    for (int i = 0; i < 7; ++i) { Wt[i] = (u16*)sm; sm += 131072; }
    float* meanB  = sm; sm += B_ * C_;
    float* stdB   = sm; sm += B_ * C_;
    float* pbuf   = sm; sm += B_ * C_ * K_;
    float* ambuf  = sm; sm += B_ * K_ * C_;
    float* recips = sm; sm += B_ * K_;
    float* cebuf  = sm; sm += K_ * H_;
    float* cnbuf  = sm; sm += K_ * H_;
    float* Qbuf   = sm; sm += K_ * H_;
    float* Ccp = F1;   // 256*8192 floats, aliases F1 (Kk dead by then)

    dim3 ggrid(4, 128);
    dim3 t_grid(B_, 16, 16);
    dim3 t_blk(32, 8);
    const int Mrows = B_ * C_;

    revin_stats<<<dim3(B_, 2), 256, 0, stream>>>(x, meanB, stdB);
    transpose_revin<<<t_grid, t_blk, 0, stream>>>(x, meanB, stdB, rev_w, rev_b, X16);
    WPtrs wp;
    wp.src[0] = mlp_w1; wp.src[1] = mlp_w2; wp.src[2] = wk; wp.src[3] = wv;
    wp.src[4] = ts_w;   wp.src[5] = ch_w1;  wp.src[6] = ch_w2;
    for (int i = 0; i < 7; ++i) wp.dst[i] = Wt[i];
    convert_w<<<dim3(16, 16, 7), t_blk, 0, stream>>>(wp);
    gemm_f32<<<dim3(8, 1), 256, 0, stream>>>(clu_emb, wq, bq, Qbuf, K_, H_, H_);
    // channel MLP
    gemm_bf16<1><<<ggrid, 256, 0, stream>>>(X16, Wt[0], mlp_b1, nullptr, T16,
                                            Mrows, H_, L_);
    gemm_bf16<5><<<ggrid, 256, 0, stream>>>(T16, Wt[1], mlp_b2, F0, X16,
                                            Mrows, H_, H_);
    // routing
    normalize_rows16<<<K_, 256, 0, stream>>>(clu_emb, cnbuf);
    routing_kernel<<<Mrows / 16, 256, 0, stream>>>(F0, cnbuf, pbuf);
    // K, V projections
    gemm_bf16<0><<<ggrid, 256, 0, stream>>>(X16, Wt[2], bk, F1, nullptr,
                                            Mrows, H_, H_);
    gemm_bf16<6><<<ggrid, 256, 0, stream>>>(X16, Wt[3], bv, nullptr, T16,
                                            Mrows, H_, H_);
    // masked attention -> ce_new
    attn_scores<<<Mrows / 16, 256, 0, stream>>>(F1, Qbuf, pbuf, ambuf);
    row_recip<<<B_ * K_, 256, 0, stream>>>(ambuf, recips);
    cc_partial<<<dim3(B_, 8), 256, 0, stream>>>(ambuf, recips, T16, Ccp);
    cc_mean<<<(K_ * H_) / 256, 256, 0, stream>>>(Ccp, cebuf);
    // mixer (fused, in [B,H,C] layout)
    transpose_b<<<t_grid, t_blk, 0, stream>>>(F0, F1);
    mixer_fused<<<Mrows / 32, 256, 0, stream>>>(F1, Wt[4], Wt[5], Wt[6],
                                                ts_ln_g, ts_ln_b, ts_b,
                                                ch_ln_g, ch_ln_b, ch_b1, ch_b2);
    transpose_b<<<t_grid, t_blk, 0, stream>>>(F1, F0);
    // expert projection + denorm
    outproj_mfma<<<C_, 256, 0, stream>>>(F0, pbuf, cebuf, out_w, out_b,
                                         rev_w, rev_b, meanB, stdB,
                                         (float*)d_out);
}

// Round 4
// 1001.138 us; speedup vs baseline: 2.7686x; 1.1686x over previous
//
#include <hip/hip_runtime.h>
#include <math.h>

#define B_  32
#define L_  512
#define C_  512
#define H_  512
#define K_  16
#define P_  96
#define NB_ 4

typedef unsigned short u16;
typedef __attribute__((ext_vector_type(8))) __bf16 bf16x8;
typedef __attribute__((ext_vector_type(4))) float f32x4;

// ---------------------------------------------------------------- helpers

__device__ __forceinline__ float gelu_f(float x) {
    return 0.5f * x * (1.0f + erff(x * 0.70710678118654752440f));
}

__device__ __forceinline__ u16 f2bf(float f) {
    union { float f; unsigned u; } v; v.f = f;
    unsigned r = v.u + 0x7fffu + ((v.u >> 16) & 1u);   // RNE
    return (u16)(r >> 16);
}
__device__ __forceinline__ float bf2f(u16 h) {
    union { unsigned u; float f; } v; v.u = ((unsigned)h) << 16;
    return v.f;
}

// block(256) dual sum reduce; call at most once per kernel
__device__ __forceinline__ void block_sum2_256(float& a, float& b) {
    __shared__ float la[4], lb[4];
    #pragma unroll
    for (int off = 32; off; off >>= 1) {
        a += __shfl_down(a, off);
        b += __shfl_down(b, off);
    }
    int wid = threadIdx.x >> 6;
    if ((threadIdx.x & 63) == 0) { la[wid] = a; lb[wid] = b; }
    __syncthreads();
    a = la[0] + la[1] + la[2] + la[3];
    b = lb[0] + lb[1] + lb[2] + lb[3];
}

// JAX threefry2x32, key = (k0,k1)
__device__ __forceinline__ void threefry2x32(unsigned k0, unsigned k1,
                                             unsigned& x0, unsigned& x1) {
    const unsigned ks0 = k0, ks1 = k1, ks2 = k0 ^ k1 ^ 0x1BD11BDAu;
    x0 += ks0; x1 += ks1;
#define TF_ROT(v, r) (((v) << (r)) | ((v) >> (32 - (r))))
#define TF_R(r) { x0 += x1; x1 = TF_ROT(x1, r); x1 ^= x0; }
    TF_R(13) TF_R(15) TF_R(26) TF_R(6)   x0 += ks1; x1 += ks2 + 1u;
    TF_R(17) TF_R(29) TF_R(16) TF_R(24)  x0 += ks2; x1 += ks0 + 2u;
    TF_R(13) TF_R(15) TF_R(26) TF_R(6)   x0 += ks0; x1 += ks1 + 3u;
    TF_R(17) TF_R(29) TF_R(16) TF_R(24)  x0 += ks1; x1 += ks2 + 4u;
    TF_R(13) TF_R(15) TF_R(26) TF_R(6)   x0 += ks2; x1 += ks0 + 5u;
#undef TF_R
#undef TF_ROT
}

#define GLL16(g, l) __builtin_amdgcn_global_load_lds( \
    (const __attribute__((address_space(1))) void*)(g), \
    (__attribute__((address_space(3))) void*)(l), 16, 0, 0)

// ---------------------------------------------------------------- kernels

// per-(b,c) mean/std over L (x is [B,L,C])
__global__ __launch_bounds__(256) void revin_stats(const float* __restrict__ x,
                                                   float* __restrict__ meanB,
                                                   float* __restrict__ stdB) {
    int b = blockIdx.x;
    int c = blockIdx.y * 256 + threadIdx.x;
    const float* xp = x + (size_t)b * L_ * C_ + c;
    float s = 0.f, ss = 0.f;
    for (int l = 0; l < L_; ++l) {
        float v = xp[(size_t)l * C_];
        s += v; ss += v * v;
    }
    float m = s * (1.0f / L_);
    float var = ss * (1.0f / L_) - m * m;
    meanB[b * C_ + c] = m;
    stdB[b * C_ + c]  = sqrtf(var + 1e-5f);
}

// x [B,L,C] -> xt bf16 [B,C,L] with RevIN applied
__global__ __launch_bounds__(256) void transpose_revin(const float* __restrict__ x,
                                                       const float* __restrict__ meanB,
                                                       const float* __restrict__ stdB,
                                                       const float* __restrict__ rw,
                                                       const float* __restrict__ rb,
                                                       u16* __restrict__ xt) {
    __shared__ float tile[32][33];
    int b = blockIdx.x, l0 = blockIdx.y * 32, c0 = blockIdx.z * 32;
    int tx = threadIdx.x, ty = threadIdx.y;
    for (int i = ty; i < 32; i += 8) {
        int l = l0 + i, c = c0 + tx;
        float v = x[((size_t)b * L_ + l) * C_ + c];
        v = (v - meanB[b * C_ + c]) / stdB[b * C_ + c] * rw[c] + rb[c];
        tile[i][tx] = v;
    }
    __syncthreads();
    for (int i = ty; i < 32; i += 8) {
        int c = c0 + i, l = l0 + tx;
        xt[((size_t)b * C_ + c) * L_ + l] = f2bf(tile[tx][i]);
    }
}

// plain per-batch 512x512 fp32 transpose
__global__ __launch_bounds__(256) void transpose_b(const float* __restrict__ in,
                                                   float* __restrict__ out) {
    __shared__ float tile[32][33];
    int b = blockIdx.x, r0 = blockIdx.y * 32, c0 = blockIdx.z * 32;
    int tx = threadIdx.x, ty = threadIdx.y;
    for (int i = ty; i < 32; i += 8)
        tile[i][tx] = in[((size_t)b * 512 + r0 + i) * 512 + c0 + tx];
    __syncthreads();
    for (int i = ty; i < 32; i += 8)
        out[((size_t)b * 512 + c0 + i) * 512 + r0 + tx] = tile[tx][i];
}

// 7 weight matrices [512][512] f32 -> transposed bf16 [512][512]
struct WPtrs { const float* src[7]; u16* dst[7]; };
__global__ __launch_bounds__(256) void convert_w(WPtrs wp) {
    __shared__ float tile[32][33];
    int wi = blockIdx.z;
    const float* src = wp.src[wi];
    u16* dst = wp.dst[wi];
    int r0 = blockIdx.y * 32, c0 = blockIdx.x * 32;
    int tx = threadIdx.x, ty = threadIdx.y;
    for (int i = ty; i < 32; i += 8)
        tile[i][tx] = src[(size_t)(r0 + i) * 512 + c0 + tx];
    __syncthreads();
    for (int i = ty; i < 32; i += 8)
        dst[(size_t)(c0 + i) * 512 + r0 + tx] = f2bf(tile[tx][i]);
}

// bf16 MFMA GEMM (m97 structure): 128x128 tile, BK=32, 256 thr (4 waves 2x2)
// EPI: 0 store f32 | 1 relu->bf16 | 5 store f32 AND bf16 | 6 store bf16
template <int EPI>
__global__ __launch_bounds__(256) void gemm_bf16(const u16* __restrict__ A,
                                                 const u16* __restrict__ Bt,
                                                 const float* __restrict__ bias,
                                                 float* __restrict__ C32,
                                                 u16* __restrict__ C16,
                                                 int M, int N, int K) {
    __shared__ u16 As[128 * 32];
    __shared__ u16 Bs[128 * 32];
    int tid = threadIdx.x;
    int m0 = blockIdx.y * 128, n0 = blockIdx.x * 128;
    int lane = tid & 63, wave = tid >> 6;
    int wm = wave >> 1, wn = wave & 1;
    int col = lane & 15, quad = lane >> 4;
    int koff = quad * 8;

    int qa0 = tid, qa1 = tid + 256;
    const u16* Ag0 = A + (size_t)(m0 + (qa0 >> 2)) * K + (qa0 & 3) * 8;
    const u16* Ag1 = A + (size_t)(m0 + (qa1 >> 2)) * K + (qa1 & 3) * 8;
    const u16* Bg0 = Bt + (size_t)(n0 + (qa0 >> 2)) * K + (qa0 & 3) * 8;
    const u16* Bg1 = Bt + (size_t)(n0 + (qa1 >> 2)) * K + (qa1 & 3) * 8;
    u16* Al0 = &As[qa0 * 8];
    u16* Al1 = &As[qa1 * 8];
    u16* Bl0 = &Bs[qa0 * 8];
    u16* Bl1 = &Bs[qa1 * 8];

    f32x4 acc[4][4];
    #pragma unroll
    for (int i = 0; i < 4; ++i)
        #pragma unroll
        for (int j = 0; j < 4; ++j)
            acc[i][j] = (f32x4){0.f, 0.f, 0.f, 0.f};

    for (int k0 = 0; k0 < K; k0 += 32) {
        GLL16(Ag0 + k0, Al0);
        GLL16(Ag1 + k0, Al1);
        GLL16(Bg0 + k0, Bl0);
        GLL16(Bg1 + k0, Bl1);
        __syncthreads();
        bf16x8 af[4], bfr[4];
        #pragma unroll
        for (int mt = 0; mt < 4; ++mt)
            af[mt] = *(const bf16x8*)&As[(wm * 64 + mt * 16 + col) * 32 + koff];
        #pragma unroll
        for (int nt = 0; nt < 4; ++nt)
            bfr[nt] = *(const bf16x8*)&Bs[(wn * 64 + nt * 16 + col) * 32 + koff];
        #pragma unroll
        for (int mt = 0; mt < 4; ++mt)
            #pragma unroll
            for (int nt = 0; nt < 4; ++nt)
                acc[mt][nt] = __builtin_amdgcn_mfma_f32_16x16x32_bf16(
                    af[mt], bfr[nt], acc[mt][nt], 0, 0, 0);
        __syncthreads();
    }

    float bb[4];
    #pragma unroll
    for (int nt = 0; nt < 4; ++nt) bb[nt] = bias[n0 + wn * 64 + nt * 16 + col];
    #pragma unroll
    for (int mt = 0; mt < 4; ++mt) {
        int mbase = m0 + wm * 64 + mt * 16 + quad * 4;
        #pragma unroll
        for (int r = 0; r < 4; ++r) {
            size_t rowoff = (size_t)(mbase + r) * N;
            #pragma unroll
            for (int nt = 0; nt < 4; ++nt) {
                int gn = n0 + wn * 64 + nt * 16 + col;
                float t = acc[mt][nt][r] + bb[nt];
                if (EPI == 1) t = fmaxf(t, 0.f);
                if (EPI == 0) {
                    C32[rowoff + gn] = t;
                } else if (EPI == 1 || EPI == 6) {
                    C16[rowoff + gn] = f2bf(t);
                } else if (EPI == 5) {
                    C32[rowoff + gn] = t;
                    C16[rowoff + gn] = f2bf(t);
                }
            }
        }
    }
}

// fp32 tiled GEMM (only for tiny Q = clu_emb @ wq + bq, M=16)
__global__ __launch_bounds__(256) void gemm_f32(const float* __restrict__ A,
                                                const float* __restrict__ Bm,
                                                const float* __restrict__ bias,
                                                float* __restrict__ Cm,
                                                int M, int N, int K) {
    __shared__ float As[16][64];
    __shared__ float Bs[16][64];
    int tid = threadIdx.x;
    int tx = tid & 15, ty = tid >> 4;
    int m0 = blockIdx.y * 64, n0 = blockIdx.x * 64;
    float acc[4][4] = {};
    for (int k0 = 0; k0 < K; k0 += 16) {
        {
            int r = tid >> 2, cc = (tid & 3) * 4, gm = m0 + r;
            float4 v = make_float4(0.f, 0.f, 0.f, 0.f);
            if (gm < M) v = *(const float4*)(A + (size_t)gm * K + k0 + cc);
            As[cc + 0][r] = v.x; As[cc + 1][r] = v.y;
            As[cc + 2][r] = v.z; As[cc + 3][r] = v.w;
        }
        {
            int r = tid >> 4, cc = (tid & 15) * 4;
            *(float4*)&Bs[r][cc] = *(const float4*)(Bm + (size_t)(k0 + r) * N + n0 + cc);
        }
        __syncthreads();
        #pragma unroll
        for (int kk = 0; kk < 16; ++kk) {
            float4 a4 = *(const float4*)&As[kk][ty * 4];
            float4 b4 = *(const float4*)&Bs[kk][tx * 4];
            float av[4] = {a4.x, a4.y, a4.z, a4.w};
            float bv[4] = {b4.x, b4.y, b4.z, b4.w};
            #pragma unroll
            for (int i = 0; i < 4; ++i)
                #pragma unroll
                for (int j = 0; j < 4; ++j)
                    acc[i][j] += av[i] * bv[j];
        }
        __syncthreads();
    }
    int gn = n0 + tx * 4;
    float4 b4 = *(const float4*)(bias + gn);
    float bb[4] = {b4.x, b4.y, b4.z, b4.w};
    #pragma unroll
    for (int i = 0; i < 4; ++i) {
        int gm = m0 + ty * 4 + i;
        if (gm >= M) break;
        float* cp = Cm + (size_t)gm * N + gn;
        *(float4*)cp = make_float4(acc[i][0] + bb[0], acc[i][1] + bb[1],
                                   acc[i][2] + bb[2], acc[i][3] + bb[3]);
    }
}

// normalize 16 rows of 512 (cluster embeds -> cn)
__global__ __launch_bounds__(256) void normalize_rows16(const float* __restrict__ ce,
                                                        float* __restrict__ cn) {
    int k = blockIdx.x, tid = threadIdx.x;
    float2 v = ((const float2*)(ce + (size_t)k * 512))[tid];
    float ss = v.x * v.x + v.y * v.y, dummy = 0.f;
    block_sum2_256(ss, dummy);
    float inv = 1.0f / fmaxf(sqrtf(ss), 1e-12f);
    float2 o; o.x = v.x * inv; o.y = v.y * inv;
    ((float2*)(cn + (size_t)k * 512))[tid] = o;
}

// p[b,c,k] = softmax_k( cos(h[b,c,:], cn[k,:]) ); block handles 16 rows
__global__ __launch_bounds__(256) void routing_kernel(const float* __restrict__ h,
                                                      const float* __restrict__ cn,
                                                      float* __restrict__ p) {
    int tid = threadIdx.x;
    int r = tid >> 4, k = tid & 15;
    int row = blockIdx.x * 16 + r;
    const float4* hp = (const float4*)(h + (size_t)row * 512);
    const float4* ck = (const float4*)(cn + (size_t)k * 512);
    float ss = 0.f;
    #pragma unroll
    for (int j = k * 8; j < k * 8 + 8; ++j) {
        float4 v = hp[j];
        ss += v.x * v.x + v.y * v.y + v.z * v.z + v.w * v.w;
    }
    #pragma unroll
    for (int off = 8; off; off >>= 1) ss += __shfl_xor(ss, off, 16);
    float inv = 1.0f / fmaxf(sqrtf(ss), 1e-12f);
    float d = 0.f;
    for (int j = 0; j < 128; ++j) {
        float4 a = hp[j], b = ck[j];
        d += a.x * b.x + a.y * b.y + a.z * b.z + a.w * b.w;
    }
    d *= inv;
    float mx = d;
    #pragma unroll
    for (int off = 8; off; off >>= 1) mx = fmaxf(mx, __shfl_xor(mx, off, 16));
    float e = expf(d - mx);
    float s = e;
    #pragma unroll
    for (int off = 8; off; off >>= 1) s += __shfl_xor(s, off, 16);
    p[(size_t)row * 16 + k] = e / s;
}

// am[b,k,c] = exp(dot(Q[k],Kk[b,c])/sqrt(H)) * bernoulli_mask; 16 rows/block
__global__ __launch_bounds__(256) void attn_scores(const float* __restrict__ Kk,
                                                   const float* __restrict__ Q,
                                                   const float* __restrict__ pbuf,
                                                   float* __restrict__ am) {
    int tid = threadIdx.x;
    int k = tid >> 4, r = tid & 15;
    int row = blockIdx.x * 16 + r;           // row = b*C + c
    int b = row >> 9, c = row & 511;
    const float4* kp = (const float4*)(Kk + (size_t)row * 512);
    const float4* qp = (const float4*)(Q + (size_t)k * 512);
    float d = 0.f;
    for (int j = 0; j < 128; ++j) {
        float4 a = kp[j], q = qp[j];
        d += a.x * q.x + a.y * q.y + a.z * q.z + a.w * q.w;
    }
    d *= 0.044194173824159216f;  // 1/sqrt(512)
    int j = row * 16 + k;
    const int HALF = (B_ * C_ * K_) / 2;
    unsigned x0 = (j < HALF) ? (unsigned)j : (unsigned)(j - HALF);
    unsigned x1 = x0 + (unsigned)HALF;
    threefry2x32(0u, 42u, x0, x1);
    unsigned bits = (j < HALF) ? x0 : x1;
    float u = __uint_as_float((bits >> 9) | 0x3f800000u) - 1.0f;
    float m = (u < pbuf[j]) ? 1.0f : 0.0f;
    am[((size_t)b * 16 + k) * 512 + c] = expf(d) * m;
}

// recip[b,k] = 1 / sum_c am[b,k,c]
__global__ __launch_bounds__(256) void row_recip(const float* __restrict__ am,
                                                 float* __restrict__ recip) {
    int rk = blockIdx.x, tid = threadIdx.x;
    float2 v = ((const float2*)(am + (size_t)rk * 512))[tid];
    float s = v.x + v.y, dummy = 0.f;
    block_sum2_256(s, dummy);
    if (tid == 0) recip[rk] = 1.0f / s;
}

// partial Cc: block (b, cs) sums c-range of 64; slab out [b*8+cs][k*512+h]
__global__ __launch_bounds__(256) void cc_partial(const float* __restrict__ am,
                                                  const float* __restrict__ recip,
                                                  const u16* __restrict__ V16,
                                                  float* __restrict__ Ccp) {
    int b = blockIdx.x, cs = blockIdx.y;
    int c0 = cs * 64, tid = threadIdx.x;
    __shared__ float awS[16 * 64];
    for (int idx = tid; idx < 1024; idx += 256) {
        int k = idx >> 6, cj = idx & 63;
        awS[idx] = am[((size_t)b * 16 + k) * 512 + c0 + cj] * recip[b * 16 + k];
    }
    __syncthreads();
    float acc0[16] = {}, acc1[16] = {};
    for (int cj = 0; cj < 64; ++cj) {
        const u16* vp = V16 + ((size_t)(b * 512) + c0 + cj) * 512;
        unsigned pk = ((const unsigned*)vp)[tid];
        float v0 = bf2f((u16)(pk & 0xffffu));
        float v1 = bf2f((u16)(pk >> 16));
        #pragma unroll
        for (int k = 0; k < 16; ++k) {
            float a = awS[k * 64 + cj];
            acc0[k] += a * v0;
            acc1[k] += a * v1;
        }
    }
    float* out = Ccp + ((size_t)(b * 8 + cs)) * 8192;
    #pragma unroll
    for (int k = 0; k < 16; ++k) {
        float2 o; o.x = acc0[k]; o.y = acc1[k];
        ((float2*)(out + k * 512))[tid] = o;
    }
}

// ce_new[k,h] = (1/B) * sum over 256 slabs
__global__ __launch_bounds__(256) void cc_mean(const float* __restrict__ Ccp,
                                               float* __restrict__ ce) {
    int idx = blockIdx.x * 256 + threadIdx.x;  // < 8192
    float s = 0.f;
    for (int sl = 0; sl < 256; ++sl) s += Ccp[(size_t)sl * 8192 + idx];
    ce[idx] = s * (1.0f / B_);
}

// ---------------------------------------------------------------- fused mixer v2
// Block = 32 rows of z [16384][512], 512 threads (8 waves), wave w owns cols
// [w*64, w*64+64). z in registers (zr 8x f32x4), LN via shfl+LDS, A via LDS
// bf16, B-fragments straight from L2-resident bf16 weights (no barriers in
// the K-loop). __launch_bounds__(512,4) caps VGPR<=128 -> 2 blocks/CU.
__global__ __launch_bounds__(512, 4) void mixer_fused2(
    float* __restrict__ z,
    const u16* __restrict__ tsw, const u16* __restrict__ chw1,
    const u16* __restrict__ chw2,
    const float* __restrict__ tslng, const float* __restrict__ tslnb,
    const float* __restrict__ tsb,
    const float* __restrict__ chlng, const float* __restrict__ chlnb,
    const float* __restrict__ chb1, const float* __restrict__ chb2) {
    __shared__ u16 A16[32 * 520];
    __shared__ float vecS[7 * 512];
    __shared__ float partS[8 * 32 * 2];
    __shared__ float statS[32 * 2];

    int tid = threadIdx.x, lane = tid & 63, w = tid >> 6;
    int col = lane & 15, quad = lane >> 4;
    int m0 = blockIdx.x * 32;
    int nb = w * 64 + col;     // base col for nt=0

    {
        const float* vsrc[7] = {tslng, tslnb, tsb, chlng, chlnb, chb1, chb2};
        for (int i = tid; i < 7 * 512; i += 512) vecS[i] = vsrc[i >> 9][i & 511];
    }

    // z rows -> registers: zr[mt*4+nt][r] = z[m0+mt*16+quad*4+r][w*64+nt*16+col]
    f32x4 zr[8];
    float* zbase = z + (size_t)m0 * 512;
    #pragma unroll
    for (int mt = 0; mt < 2; ++mt)
        #pragma unroll
        for (int nt = 0; nt < 4; ++nt)
            #pragma unroll
            for (int r = 0; r < 4; ++r)
                zr[mt * 4 + nt][r] =
                    zbase[(size_t)(mt * 16 + quad * 4 + r) * 512 + nb + nt * 16];

    auto stats = [&]() {
        #pragma unroll
        for (int mt = 0; mt < 2; ++mt)
            #pragma unroll
            for (int r = 0; r < 4; ++r) {
                float s = 0.f, ss = 0.f;
                #pragma unroll
                for (int nt = 0; nt < 4; ++nt) {
                    float v = zr[mt * 4 + nt][r];
                    s += v; ss += v * v;
                }
                #pragma unroll
                for (int o = 8; o; o >>= 1) {
                    s += __shfl_xor(s, o, 16);
                    ss += __shfl_xor(ss, o, 16);
                }
                if (col == 0) {
                    int m = mt * 16 + quad * 4 + r;
                    partS[(w * 32 + m) * 2 + 0] = s;
                    partS[(w * 32 + m) * 2 + 1] = ss;
                }
            }
        __syncthreads();
        if (tid < 32) {
            float s = 0.f, ss = 0.f;
            #pragma unroll
            for (int wv = 0; wv < 8; ++wv) {
                s += partS[(wv * 32 + tid) * 2];
                ss += partS[(wv * 32 + tid) * 2 + 1];
            }
            float mean = s * (1.0f / 512.0f);
            float var = ss * (1.0f / 512.0f) - mean * mean;
            statS[tid * 2] = mean;
            statS[tid * 2 + 1] = rsqrtf(var + 1e-5f);
        }
        __syncthreads();
    };

    auto writeNorm = [&](int gi, int bi) {
        #pragma unroll
        for (int nt = 0; nt < 4; ++nt) {
            int n = nb + nt * 16;
            float g = vecS[gi * 512 + n], bb = vecS[bi * 512 + n];
            #pragma unroll
            for (int mt = 0; mt < 2; ++mt)
                #pragma unroll
                for (int r = 0; r < 4; ++r) {
                    int m = mt * 16 + quad * 4 + r;
                    float v = (zr[mt * 4 + nt][r] - statS[m * 2]) *
                              statS[m * 2 + 1] * g + bb;
                    A16[m * 520 + n] = f2bf(v);
                }
        }
        __syncthreads();
    };

    f32x4 acc[8];
    auto gemm = [&](const u16* __restrict__ W) {
        #pragma unroll
        for (int i = 0; i < 8; ++i) acc[i] = (f32x4){0.f, 0.f, 0.f, 0.f};
        const u16* wb = W + (size_t)nb * 512 + quad * 8;
        #pragma unroll 4
        for (int kc = 0; kc < 16; ++kc) {
            bf16x8 b0 = *(const bf16x8*)&wb[kc * 32];
            bf16x8 b1 = *(const bf16x8*)&wb[16 * 512 + kc * 32];
            bf16x8 b2 = *(const bf16x8*)&wb[32 * 512 + kc * 32];
            bf16x8 b3 = *(const bf16x8*)&wb[48 * 512 + kc * 32];
            bf16x8 a0 = *(const bf16x8*)&A16[col * 520 + kc * 32 + quad * 8];
            bf16x8 a1 = *(const bf16x8*)&A16[(16 + col) * 520 + kc * 32 + quad * 8];
            acc[0] = __builtin_amdgcn_mfma_f32_16x16x32_bf16(a0, b0, acc[0], 0, 0, 0);
            acc[1] = __builtin_amdgcn_mfma_f32_16x16x32_bf16(a0, b1, acc[1], 0, 0, 0);
            acc[2] = __builtin_amdgcn_mfma_f32_16x16x32_bf16(a0, b2, acc[2], 0, 0, 0);
            acc[3] = __builtin_amdgcn_mfma_f32_16x16x32_bf16(a0, b3, acc[3], 0, 0, 0);
            acc[4] = __builtin_amdgcn_mfma_f32_16x16x32_bf16(a1, b0, acc[4], 0, 0, 0);
            acc[5] = __builtin_amdgcn_mfma_f32_16x16x32_bf16(a1, b1, acc[5], 0, 0, 0);
            acc[6] = __builtin_amdgcn_mfma_f32_16x16x32_bf16(a1, b2, acc[6], 0, 0, 0);
            acc[7] = __builtin_amdgcn_mfma_f32_16x16x32_bf16(a1, b3, acc[7], 0, 0, 0);
        }
    };

    for (int it = 0; it < NB_; ++it) {
        // z += gelu(LN_ts(z) @ ts_w + ts_b)
        stats();
        writeNorm(0, 1);
        gemm(tsw);
        #pragma unroll
        for (int nt = 0; nt < 4; ++nt) {
            float bb = vecS[2 * 512 + nb + nt * 16];
            #pragma unroll
            for (int mt = 0; mt < 2; ++mt)
                #pragma unroll
                for (int r = 0; r < 4; ++r)
                    zr[mt * 4 + nt][r] += gelu_f(acc[mt * 4 + nt][r] + bb);
        }
        // z += gelu(LN_ch(z) @ ch_w1 + ch_b1) @ ch_w2 + ch_b2
        stats();                       // barrier also fences A16 reads
        writeNorm(3, 4);
        gemm(chw1);
        __syncthreads();               // all waves done reading A16
        #pragma unroll
        for (int nt = 0; nt < 4; ++nt) {
            int n = nb + nt * 16;
            float bb = vecS[5 * 512 + n];
            #pragma unroll
            for (int mt = 0; mt < 2; ++mt)
                #pragma unroll
                for (int r = 0; r < 4; ++r) {
                    int m = mt * 16 + quad * 4 + r;
                    A16[m * 520 + n] = f2bf(gelu_f(acc[mt * 4 + nt][r] + bb));
                }
        }
        __syncthreads();
        gemm(chw2);
        #pragma unroll
        for (int nt = 0; nt < 4; ++nt) {
            float bb = vecS[6 * 512 + nb + nt * 16];
            #pragma unroll
            for (int mt = 0; mt < 2; ++mt)
                #pragma unroll
                for (int r = 0; r < 4; ++r)
                    zr[mt * 4 + nt][r] += acc[mt * 4 + nt][r] + bb;
        }
        __syncthreads();               // fence before next iter's A16 write
    }

    #pragma unroll
    for (int mt = 0; mt < 2; ++mt)
        #pragma unroll
        for (int nt = 0; nt < 4; ++nt)
            #pragma unroll
            for (int r = 0; r < 4; ++r)
                zbase[(size_t)(mt * 16 + quad * 4 + r) * 512 + nb + nt * 16] =
                    zr[mt * 4 + nt][r];
}

// ---------------------------------------------------------------- out proj
__global__ __launch_bounds__(256) void outproj_mfma(
    const float* __restrict__ Hm, const float* __restrict__ pbuf,
    const float* __restrict__ ce, const float* __restrict__ out_w,
    const float* __restrict__ out_b, const float* __restrict__ rev_w,
    const float* __restrict__ rev_b, const float* __restrict__ meanB,
    const float* __restrict__ stdB, float* __restrict__ out) {
    __shared__ float pS[32 * 16];
    __shared__ u16 A16[32 * 520];
    __shared__ u16 Bs[4][96 * 40];
    __shared__ float redS[4][32 * 96];

    int c = blockIdx.x, tid = threadIdx.x;
    int lane = tid & 63, wave = tid >> 6;
    int col = lane & 15, quad = lane >> 4;

    for (int idx = tid; idx < 512; idx += 256) {
        int b = idx >> 4, k = idx & 15;
        pS[idx] = pbuf[((size_t)(b * 512 + c)) * 16 + k];
    }
    __syncthreads();

    {
        int h0 = lane * 8;
        f32x4 th[8][2];
        #pragma unroll
        for (int b = 0; b < 8; ++b) {
            th[b][0] = (f32x4){0.f, 0.f, 0.f, 0.f};
            th[b][1] = (f32x4){0.f, 0.f, 0.f, 0.f};
        }
        for (int k = 0; k < 16; ++k) {
            f32x4 ce0 = *(const f32x4*)&ce[k * 512 + h0];
            f32x4 ce1 = *(const f32x4*)&ce[k * 512 + h0 + 4];
            #pragma unroll
            for (int b = 0; b < 8; ++b) {
                float pk = pS[(wave * 8 + b) * 16 + k];
                th[b][0] += ce0 * pk;
                th[b][1] += ce1 * pk;
            }
        }
        #pragma unroll
        for (int b = 0; b < 8; ++b) {
            int bb = wave * 8 + b;
            const f32x4* hp = (const f32x4*)&Hm[((size_t)(bb * 512 + c)) * 512 + h0];
            f32x4 g0 = hp[0] * th[b][0];
            f32x4 g1 = hp[1] * th[b][1];
            ushort4 o0, o1;
            o0.x = f2bf(g0[0]); o0.y = f2bf(g0[1]); o0.z = f2bf(g0[2]); o0.w = f2bf(g0[3]);
            o1.x = f2bf(g1[0]); o1.y = f2bf(g1[1]); o1.z = f2bf(g1[2]); o1.w = f2bf(g1[3]);
            *(ushort4*)&A16[bb * 520 + h0] = o0;
            *(ushort4*)&A16[bb * 520 + h0 + 4] = o1;
        }
    }
    __syncthreads();

    f32x4 pacc[12];
    #pragma unroll
    for (int i = 0; i < 12; ++i) pacc[i] = (f32x4){0.f, 0.f, 0.f, 0.f};
    const size_t wbase = (size_t)c * 512 * 96;
    for (int i = 0; i < 4; ++i) {
        int kc = wave * 4 + i;
        {
            const float4* wsrc = (const float4*)(out_w + wbase + (size_t)kc * 32 * 96);
            #pragma unroll
            for (int t = 0; t < 12; ++t) {
                int flat4 = lane + t * 64;
                float4 v = wsrc[flat4];
                int kk = flat4 / 24, p4 = (flat4 % 24) * 4;
                Bs[wave][(p4 + 0) * 40 + kk] = f2bf(v.x);
                Bs[wave][(p4 + 1) * 40 + kk] = f2bf(v.y);
                Bs[wave][(p4 + 2) * 40 + kk] = f2bf(v.z);
                Bs[wave][(p4 + 3) * 40 + kk] = f2bf(v.w);
            }
        }
        __syncthreads();
        #pragma unroll
        for (int mt = 0; mt < 2; ++mt) {
            bf16x8 a = *(const bf16x8*)&A16[(mt * 16 + col) * 520 + kc * 32 + quad * 8];
            #pragma unroll
            for (int nt = 0; nt < 6; ++nt) {
                bf16x8 bf = *(const bf16x8*)&Bs[wave][(nt * 16 + col) * 40 + quad * 8];
                pacc[mt * 6 + nt] = __builtin_amdgcn_mfma_f32_16x16x32_bf16(
                    a, bf, pacc[mt * 6 + nt], 0, 0, 0);
            }
        }
        __syncthreads();
    }
    #pragma unroll
    for (int mt = 0; mt < 2; ++mt)
        #pragma unroll
        for (int nt = 0; nt < 6; ++nt)
            #pragma unroll
            for (int r = 0; r < 4; ++r) {
                int b = mt * 16 + quad * 4 + r;
                int p = nt * 16 + col;
                redS[wave][b * 96 + p] = pacc[mt * 6 + nt][r];
            }
    __syncthreads();

    float inv_rw = 1.0f / (rev_w[c] + 1e-10f);
    float rb = rev_b[c];
    for (int e = tid; e < 3072; e += 256) {
        float v = redS[0][e] + redS[1][e] + redS[2][e] + redS[3][e];
        int b = e / 96, p = e - b * 96;
        v += out_b[(size_t)c * 96 + p];
        float y = (v - rb) * inv_rw * stdB[b * 512 + c] + meanB[b * 512 + c];
        out[((size_t)b * 96 + p) * 512 + c] = y;
    }
}

// ---------------------------------------------------------------- launch

extern "C" void kernel_launch(void* const* d_in, const int* in_sizes, int n_in,
                              void* d_out, int out_size, void* d_ws, size_t ws_size,
                              hipStream_t stream) {
    const float* x        = (const float*)d_in[0];
    const float* rev_w    = (const float*)d_in[1];
    const float* rev_b    = (const float*)d_in[2];
    const float* mlp_w1   = (const float*)d_in[3];
    const float* mlp_b1   = (const float*)d_in[4];
    const float* mlp_w2   = (const float*)d_in[5];
    const float* mlp_b2   = (const float*)d_in[6];
    const float* clu_emb  = (const float*)d_in[7];
    const float* wq       = (const float*)d_in[8];
    const float* bq       = (const float*)d_in[9];
    const float* wk       = (const float*)d_in[10];
    const float* bk       = (const float*)d_in[11];
    const float* wv       = (const float*)d_in[12];
    const float* bv       = (const float*)d_in[13];
    const float* ts_ln_g  = (const float*)d_in[14];
    const float* ts_ln_b  = (const float*)d_in[15];
    const float* ts_w     = (const float*)d_in[16];
    const float* ts_b     = (const float*)d_in[17];
    const float* ch_ln_g  = (const float*)d_in[18];
    const float* ch_ln_b  = (const float*)d_in[19];
    const float* ch_w1    = (const float*)d_in[20];
    const float* ch_b1    = (const float*)d_in[21];
    const float* ch_w2    = (const float*)d_in[22];
    const float* ch_b2    = (const float*)d_in[23];
    const float* out_w    = (const float*)d_in[24];
    const float* out_b    = (const float*)d_in[25];

    float* f = (float*)d_ws;
    const size_t SLOT = (size_t)(B_ * C_) * H_;   // 8388608 floats
    float* F0 = f;                                // h32 -> Hm32
    float* F1 = f + SLOT;                         // Kk32 -> Ccp -> z
    u16*  X16 = (u16*)(f + 2 * SLOT);             // xt -> h16
    u16*  T16 = (u16*)(f + 2 * SLOT + SLOT / 2);  // t -> V16
    float* sm = f + 3 * SLOT;
    u16* Wt[7];
    for (int i = 0; i < 7; ++i) { Wt[i] = (u16*)sm; sm += 131072; }
    float* meanB  = sm; sm += B_ * C_;
    float* stdB   = sm; sm += B_ * C_;
    float* pbuf   = sm; sm += B_ * C_ * K_;
    float* ambuf  = sm; sm += B_ * K_ * C_;
    float* recips = sm; sm += B_ * K_;
    float* cebuf  = sm; sm += K_ * H_;
    float* cnbuf  = sm; sm += K_ * H_;
    float* Qbuf   = sm; sm += K_ * H_;
    float* Ccp = F1;

    dim3 ggrid(4, 128);
    dim3 t_grid(B_, 16, 16);
    dim3 t_blk(32, 8);
    const int Mrows = B_ * C_;

    revin_stats<<<dim3(B_, 2), 256, 0, stream>>>(x, meanB, stdB);
    transpose_revin<<<t_grid, t_blk, 0, stream>>>(x, meanB, stdB, rev_w, rev_b, X16);
    WPtrs wp;
    wp.src[0] = mlp_w1; wp.src[1] = mlp_w2; wp.src[2] = wk; wp.src[3] = wv;
    wp.src[4] = ts_w;   wp.src[5] = ch_w1;  wp.src[6] = ch_w2;
    for (int i = 0; i < 7; ++i) wp.dst[i] = Wt[i];
    convert_w<<<dim3(16, 16, 7), t_blk, 0, stream>>>(wp);
    gemm_f32<<<dim3(8, 1), 256, 0, stream>>>(clu_emb, wq, bq, Qbuf, K_, H_, H_);
    // channel MLP
    gemm_bf16<1><<<ggrid, 256, 0, stream>>>(X16, Wt[0], mlp_b1, nullptr, T16,
                                            Mrows, H_, L_);
    gemm_bf16<5><<<ggrid, 256, 0, stream>>>(T16, Wt[1], mlp_b2, F0, X16,
                                            Mrows, H_, H_);
    // routing
    normalize_rows16<<<K_, 256, 0, stream>>>(clu_emb, cnbuf);
    routing_kernel<<<Mrows / 16, 256, 0, stream>>>(F0, cnbuf, pbuf);
    // K, V projections
    gemm_bf16<0><<<ggrid, 256, 0, stream>>>(X16, Wt[2], bk, F1, nullptr,
                                            Mrows, H_, H_);
    gemm_bf16<6><<<ggrid, 256, 0, stream>>>(X16, Wt[3], bv, nullptr, T16,
                                            Mrows, H_, H_);
    // masked attention -> ce_new
    attn_scores<<<Mrows / 16, 256, 0, stream>>>(F1, Qbuf, pbuf, ambuf);
    row_recip<<<B_ * K_, 256, 0, stream>>>(ambuf, recips);
    cc_partial<<<dim3(B_, 8), 256, 0, stream>>>(ambuf, recips, T16, Ccp);
    cc_mean<<<(K_ * H_) / 256, 256, 0, stream>>>(Ccp, cebuf);
    // mixer (fused v2, [B,H,C] layout)
    transpose_b<<<t_grid, t_blk, 0, stream>>>(F0, F1);
    mixer_fused2<<<Mrows / 32, 512, 0, stream>>>(F1, Wt[4], Wt[5], Wt[6],
                                                 ts_ln_g, ts_ln_b, ts_b,
                                                 ch_ln_g, ch_ln_b, ch_b1, ch_b2);
    transpose_b<<<t_grid, t_blk, 0, stream>>>(F1, F0);
    // expert projection + denorm
    outproj_mfma<<<C_, 256, 0, stream>>>(F0, pbuf, cebuf, out_w, out_b,
                                         rev_w, rev_b, meanB, stdB,
                                         (float*)d_out);
}